// Round 13
// baseline (492.896 us; speedup 1.0000x reference)
//
#include <hip/hip_runtime.h>
#include <hip/hip_fp16.h>
#include <float.h>

#define BB 8
#define NN 4096
#define DD 64
#define KNBR 10
#define ROWS (BB*NN)   // 32768

typedef _Float16 f16x8 __attribute__((ext_vector_type(8)));
typedef float f32x4 __attribute__((ext_vector_type(4)));

// ---------------- K1: BN stats (sum, sumsq per feature) ----------------
__global__ void k_bn_stats(const float* __restrict__ x, float* __restrict__ stats) {
  __shared__ float ls[2][4][64];
  int d = threadIdx.x & 63;
  int g = threadIdx.x >> 6;
  float s = 0.f, s2 = 0.f;
  for (int r = blockIdx.x * 4 + g; r < ROWS; r += gridDim.x * 4) {
    float val = x[r * 64 + d];
    s += val;
    s2 = fmaf(val, val, s2);
  }
  ls[0][g][d] = s;
  ls[1][g][d] = s2;
  __syncthreads();
  if (g == 0) {
    atomicAdd(&stats[d],      ls[0][0][d] + ls[0][1][d] + ls[0][2][d] + ls[0][3][d]);
    atomicAdd(&stats[64 + d], ls[1][0][d] + ls[1][1][d] + ls[1][2][d] + ls[1][3][d]);
  }
}

// ---------------- K2: finalize scale/shift ----------------
__global__ void k_bn_finalize(const float* __restrict__ stats,
                              const float* __restrict__ gamma,
                              const float* __restrict__ beta,
                              float* __restrict__ ss) {
  int d = threadIdx.x;  // 64 threads
  const float inv = 1.f / 32768.f;
  float mu  = stats[d] * inv;
  float var = stats[64 + d] * inv - mu * mu;
  float sc  = gamma[d] / sqrtf(var + 1e-5f);
  ss[d]      = sc;
  ss[64 + d] = beta[d] - mu * sc;
}

// ---------------- K3: normalize + row sumsq + f16 hi/lo planes ----------------
__global__ void k_normalize(const float* __restrict__ x, const float* __restrict__ ss,
                            float* __restrict__ xn, float* __restrict__ sq,
                            _Float16* __restrict__ xh, _Float16* __restrict__ xl) {
  int row = blockIdx.x * 4 + (threadIdx.x >> 6);
  int d = threadIdx.x & 63;
  int idx = row * 64 + d;
  float val = fmaf(x[idx], ss[d], ss[64 + d]);
  xn[idx] = val;
  _Float16 h = (_Float16)val;
  _Float16 l = (_Float16)(val - (float)h);
  xh[idx] = h;
  xl[idx] = l;
  float p = val * val;
  #pragma unroll
  for (int off = 32; off > 0; off >>= 1) p += __shfl_xor(p, off);
  if (d == 0) sq[row] = p;
}

// ---------------- K4: KNN, exact two-pass, 32-query tiles (grid 1024) ----------------
// Round-7 structure (staging + sh/sl prefetch, values-only med3 ladder, exact
// threshold + recompute pass B) with the grid-cap lever applied: 32-row query
// tiles double the grid to 1024 (4 blocks/CU offered) and halve Dw so LDS/block
// ~= 50 KB -> 3 blocks/CU resident = 12 waves/CU (was 8). Scan: lanes r and
// r+32 process disjoint 16-m halves of Dw row r, merged once via shfl_xor(32)
// (merge pattern verified in round 9).
__global__ __launch_bounds__(256, 2) void k_knn(const _Float16* __restrict__ xh,
                                                const _Float16* __restrict__ xl,
                                                const float* __restrict__ sq,
                                                int* __restrict__ knn) {
  __shared__ __align__(16) char lds[49664];   // 4 waves x (4096+4096+4224)
  __shared__ float thrs[32];
  __shared__ int cnts[32];
  const int tid = threadIdx.x;
  const int w = tid >> 6, lane = tid & 63;
  const int l15 = lane & 15, lg = lane >> 4;
  const int b = blockIdx.x >> 7;              // 8 batches
  const int rowbase = (blockIdx.x & 127) << 5; // 128 query tiles of 32
  const int bN = b * NN;
  const _Float16* __restrict__ xhb = xh + (size_t)bN * 64;
  const _Float16* __restrict__ xlb = xl + (size_t)bN * 64;

  char* wbase = lds + w * 12416;
  char* Bhi = wbase;                    // 32 m-rows x 64 f16, XOR-swizzled
  char* Blo = wbase + 4096;
  float* Dw = (float*)(wbase + 8192);   // [32][33] floats (4224 B)

  // A fragments: this block's 32 query rows (2 mt tiles), persistent
  f16x8 Ah[2][2], Al[2][2];
  #pragma unroll
  for (int mt = 0; mt < 2; ++mt) {
    #pragma unroll
    for (int ks = 0; ks < 2; ++ks) {
      int r = rowbase + mt * 16 + l15;
      Ah[mt][ks] = *(const f16x8*)(xhb + r * 64 + ks * 32 + lg * 8);
      Al[mt][ks] = *(const f16x8*)(xlb + r * 64 + ks * 32 + lg * 8);
    }
  }

  float bd[10];
  #pragma unroll
  for (int i = 0; i < 10; ++i) bd[i] = FLT_MAX;

  // staging chunk coords (tile = 32 m-rows x 64 f16 = 256 chunks of 8 f16)
  int srow[4], scc[4];
  #pragma unroll
  for (int i = 0; i < 4; ++i) { int c = i * 64 + lane; srow[i] = c >> 3; scc[i] = c & 7; }

  f16x8 sh[4], sl[4];
  {
    int mb0 = w * 32;
    #pragma unroll
    for (int i = 0; i < 4; ++i) {
      sh[i] = *(const f16x8*)(xhb + (mb0 + srow[i]) * 64 + scc[i] * 8);
      sl[i] = *(const f16x8*)(xlb + (mb0 + srow[i]) * 64 + scc[i] * 8);
    }
  }

  // scan split: lane handles row (lane&31), half (lane>>5)
  const int rr = lane & 31, hh = lane >> 5;
  float* Drow = Dw + rr * 33 + hh * 16;

  // ---------------- PASS A: values-only top-10 ----------------
  #pragma unroll 1
  for (int t = 0; t < 32; ++t) {
    const int mb = (t * 4 + w) * 32;
    const int mb2 = (t < 31) ? ((t + 1) * 4 + w) * 32 : mb;
    float sqv0 = sq[bN + mb + l15];
    float sqv1 = sq[bN + mb + 16 + l15];
    #pragma unroll
    for (int i = 0; i < 4; ++i) {
      int off = srow[i] * 128 + 16 * (scc[i] ^ (srow[i] & 7));
      *(f16x8*)(Bhi + off) = sh[i];
      *(f16x8*)(Blo + off) = sl[i];
    }
    #pragma unroll
    for (int i = 0; i < 4; ++i) {
      sh[i] = *(const f16x8*)(xhb + (mb2 + srow[i]) * 64 + scc[i] * 8);
      sl[i] = *(const f16x8*)(xlb + (mb2 + srow[i]) * 64 + scc[i] * 8);
    }
    f16x8 Bh[2][2], Bl[2][2];
    #pragma unroll
    for (int nt = 0; nt < 2; ++nt) {
      #pragma unroll
      for (int ks = 0; ks < 2; ++ks) {
        int rr2 = nt * 16 + l15;
        int off = rr2 * 128 + 16 * ((ks * 4 + lg) ^ (rr2 & 7));
        Bh[nt][ks] = *(const f16x8*)(Bhi + off);
        Bl[nt][ks] = *(const f16x8*)(Blo + off);
      }
    }
    #pragma unroll
    for (int mt = 0; mt < 2; ++mt) {
      f32x4 a0 = {0.f, 0.f, 0.f, 0.f}, a1 = {0.f, 0.f, 0.f, 0.f};
      #pragma unroll
      for (int ks = 0; ks < 2; ++ks) {
        a0 = __builtin_amdgcn_mfma_f32_16x16x32_f16(Ah[mt][ks], Bh[0][ks], a0, 0, 0, 0);
        a1 = __builtin_amdgcn_mfma_f32_16x16x32_f16(Ah[mt][ks], Bh[1][ks], a1, 0, 0, 0);
        a0 = __builtin_amdgcn_mfma_f32_16x16x32_f16(Ah[mt][ks], Bl[0][ks], a0, 0, 0, 0);
        a1 = __builtin_amdgcn_mfma_f32_16x16x32_f16(Ah[mt][ks], Bl[1][ks], a1, 0, 0, 0);
        a0 = __builtin_amdgcn_mfma_f32_16x16x32_f16(Al[mt][ks], Bh[0][ks], a0, 0, 0, 0);
        a1 = __builtin_amdgcn_mfma_f32_16x16x32_f16(Al[mt][ks], Bh[1][ks], a1, 0, 0, 0);
      }
      int rw = mt * 16 + lg * 4;
      #pragma unroll
      for (int r2 = 0; r2 < 4; ++r2) {
        Dw[(rw + r2) * 33 + l15]      = fmaf(-2.f, a0[r2], sqv0);
        Dw[(rw + r2) * 33 + 16 + l15] = fmaf(-2.f, a1[r2], sqv1);
      }
    }
    // scan 16 m's per lane (row rr, half hh)
    #pragma unroll 4
    for (int mm = 0; mm < 16; ++mm) {
      float cd = Drow[mm];
      if (cd < bd[9]) {
        float prev = bd[0];
        bd[0] = fminf(cd, bd[0]);
        #pragma unroll
        for (int j = 1; j < 10; ++j) {
          float cur = bd[j];
          bd[j] = fminf(cur, fmaxf(prev, cd));   // -> v_med3_f32
          prev = cur;
        }
      }
    }
  }

  // merge the two half-lists of each row (shfl_xor(32), round-9 pattern)
  {
    float ov[10];
    #pragma unroll
    for (int i = 0; i < 10; ++i) ov[i] = __shfl_xor(bd[i], 32);
    #pragma unroll
    for (int i = 0; i < 10; ++i) {
      float cd = ov[i];
      if (cd < bd[9]) {
        float prev = bd[0];
        bd[0] = fminf(cd, bd[0]);
        #pragma unroll
        for (int j = 1; j < 10; ++j) {
          float cur = bd[j];
          bd[j] = fminf(cur, fmaxf(prev, cd));
          prev = cur;
        }
      }
    }
  }

  // ---------------- merge 4 wave-lists -> per-row exact threshold ----------------
  __syncthreads();
  float* md = (float*)lds;   // [4][32][10]
  if (lane < 32) {
    #pragma unroll
    for (int i = 0; i < 10; ++i) md[(w * 32 + rr) * 10 + i] = bd[i];
  }
  if (tid < 32) cnts[tid] = 0;
  __syncthreads();
  if (tid < 32) {
    float fd[10];
    #pragma unroll
    for (int i = 0; i < 10; ++i) fd[i] = FLT_MAX;
    for (int w2 = 0; w2 < 4; ++w2) {
      #pragma unroll 1
      for (int kk = 0; kk < 10; ++kk) {
        float cd = md[(w2 * 32 + tid) * 10 + kk];
        if (cd < fd[9]) {
          float prev = fd[0];
          fd[0] = fminf(cd, fd[0]);
          #pragma unroll
          for (int j = 1; j < 10; ++j) {
            float cur = fd[j];
            fd[j] = fminf(cur, fmaxf(prev, cd));
            prev = cur;
          }
        } else break;   // lists sorted ascending
      }
    }
    thrs[tid] = fd[9];
  }
  __syncthreads();

  // per-lane thresholds for its 8 output rows
  float thv[2][4];
  #pragma unroll
  for (int mt = 0; mt < 2; ++mt)
    #pragma unroll
    for (int r2 = 0; r2 < 4; ++r2)
      thv[mt][r2] = thrs[mt * 16 + lg * 4 + r2];

  int* knnrow = knn + (size_t)(bN + rowbase) * KNBR;

  // ---------------- PASS B: recompute + threshold-append ----------------
  {
    int mb0 = w * 32;
    #pragma unroll
    for (int i = 0; i < 4; ++i) {
      sh[i] = *(const f16x8*)(xhb + (mb0 + srow[i]) * 64 + scc[i] * 8);
      sl[i] = *(const f16x8*)(xlb + (mb0 + srow[i]) * 64 + scc[i] * 8);
    }
  }
  #pragma unroll 1
  for (int t = 0; t < 32; ++t) {
    const int mb = (t * 4 + w) * 32;
    const int mb2 = (t < 31) ? ((t + 1) * 4 + w) * 32 : mb;
    float sqv0 = sq[bN + mb + l15];
    float sqv1 = sq[bN + mb + 16 + l15];
    #pragma unroll
    for (int i = 0; i < 4; ++i) {
      int off = srow[i] * 128 + 16 * (scc[i] ^ (srow[i] & 7));
      *(f16x8*)(Bhi + off) = sh[i];
      *(f16x8*)(Blo + off) = sl[i];
    }
    #pragma unroll
    for (int i = 0; i < 4; ++i) {
      sh[i] = *(const f16x8*)(xhb + (mb2 + srow[i]) * 64 + scc[i] * 8);
      sl[i] = *(const f16x8*)(xlb + (mb2 + srow[i]) * 64 + scc[i] * 8);
    }
    f16x8 Bh[2][2], Bl[2][2];
    #pragma unroll
    for (int nt = 0; nt < 2; ++nt) {
      #pragma unroll
      for (int ks = 0; ks < 2; ++ks) {
        int rr2 = nt * 16 + l15;
        int off = rr2 * 128 + 16 * ((ks * 4 + lg) ^ (rr2 & 7));
        Bh[nt][ks] = *(const f16x8*)(Bhi + off);
        Bl[nt][ks] = *(const f16x8*)(Blo + off);
      }
    }
    #pragma unroll
    for (int mt = 0; mt < 2; ++mt) {
      f32x4 a0 = {0.f, 0.f, 0.f, 0.f}, a1 = {0.f, 0.f, 0.f, 0.f};
      #pragma unroll
      for (int ks = 0; ks < 2; ++ks) {
        a0 = __builtin_amdgcn_mfma_f32_16x16x32_f16(Ah[mt][ks], Bh[0][ks], a0, 0, 0, 0);
        a1 = __builtin_amdgcn_mfma_f32_16x16x32_f16(Ah[mt][ks], Bh[1][ks], a1, 0, 0, 0);
        a0 = __builtin_amdgcn_mfma_f32_16x16x32_f16(Ah[mt][ks], Bl[0][ks], a0, 0, 0, 0);
        a1 = __builtin_amdgcn_mfma_f32_16x16x32_f16(Ah[mt][ks], Bl[1][ks], a1, 0, 0, 0);
        a0 = __builtin_amdgcn_mfma_f32_16x16x32_f16(Al[mt][ks], Bh[0][ks], a0, 0, 0, 0);
        a1 = __builtin_amdgcn_mfma_f32_16x16x32_f16(Al[mt][ks], Bh[1][ks], a1, 0, 0, 0);
      }
      #pragma unroll
      for (int r2 = 0; r2 < 4; ++r2) {
        float d0 = fmaf(-2.f, a0[r2], sqv0);
        float d1 = fmaf(-2.f, a1[r2], sqv1);
        int row = mt * 16 + lg * 4 + r2;
        if (d0 <= thv[mt][r2]) {
          int slot = atomicAdd(&cnts[row], 1);
          if (slot < KNBR) knnrow[row * KNBR + slot] = bN + mb + l15;
        }
        if (d1 <= thv[mt][r2]) {
          int slot = atomicAdd(&cnts[row], 1);
          if (slot < KNBR) knnrow[row * KNBR + slot] = bN + mb + 16 + l15;
        }
      }
    }
  }
}

// ---------------- K5: U/V precompute (layer-1 folded per point) ----------------
__global__ void k_uv(const float* __restrict__ xn, const float* __restrict__ W1,
                     const float* __restrict__ b1, float* __restrict__ u,
                     float* __restrict__ v) {
  __shared__ float xs[64 * 64];   // 16 KB
  const int tid = threadIdx.x;
  const int o = tid & 127;
  const bool isU = tid < 128;
  const int rowbase = blockIdx.x * 64;

  float wreg[64];
  #pragma unroll
  for (int d = 0; d < 64; ++d) {
    float bw = W1[(64 + d) * 128 + o];
    wreg[d] = isU ? (W1[d * 128 + o] + bw) : bw;
  }
  const float bb = isU ? b1[o] : 0.f;
  float* __restrict__ dst = isU ? u : v;

  {
    const float4* s4 = (const float4*)(xn + rowbase * 64);
    float4* d4 = (float4*)xs;
    #pragma unroll
    for (int i = 0; i < 4; ++i) d4[tid + 256 * i] = s4[tid + 256 * i];
  }
  __syncthreads();

  for (int r = 0; r < 64; ++r) {
    const float4* xr = (const float4*)(xs + r * 64);
    float a0 = bb, a1 = 0.f, a2 = 0.f, a3 = 0.f;
    #pragma unroll
    for (int q = 0; q < 16; ++q) {
      float4 xv = xr[q];
      a0 = fmaf(xv.x, wreg[4 * q + 0], a0);
      a1 = fmaf(xv.y, wreg[4 * q + 1], a1);
      a2 = fmaf(xv.z, wreg[4 * q + 2], a2);
      a3 = fmaf(xv.w, wreg[4 * q + 3], a3);
    }
    dst[(rowbase + r) * 128 + o] = (a0 + a1) + (a2 + a3);
  }
}

// ---------------- K6: edge MLP via MFMA, barrier-free per-wave ----------------
// grid 1024: each wave owns ONE group of 8 points (4096 groups).
__global__ __launch_bounds__(256, 2) void k_edge(const float* __restrict__ uu,
                                                 const float* __restrict__ vv,
                                                 const int* __restrict__ knn,
                                                 const float* __restrict__ W2,
                                                 const float* __restrict__ b2,
                                                 const float* __restrict__ W3,
                                                 const float* __restrict__ b3,
                                                 float* __restrict__ vert) {
  __shared__ __align__(16) _Float16 W3Ts[64 * 72];        // W3T[out][k2], 9216 B
  __shared__ __align__(16) _Float16 h2buf[4][16 * 88];    // per-wave, 2816 B each
  __shared__ int vmaxs[4][512];                           // per-wave [8 pts][64]
  const int tid = threadIdx.x;
  const int w = tid >> 6, lane = tid & 63;
  const int l15 = lane & 15, lg = lane >> 4;

  for (int i = tid; i < 64 * 64; i += 256) {
    int o3 = i >> 6, k2 = i & 63;
    W3Ts[o3 * 72 + k2] = (_Float16)W3[k2 * 64 + o3];
  }
  f16x8 w2f[4][4];
  #pragma unroll
  for (int ks = 0; ks < 4; ++ks) {
    #pragma unroll
    for (int nt = 0; nt < 4; ++nt) {
      f16x8 t;
      #pragma unroll
      for (int j = 0; j < 8; ++j)
        t[j] = (_Float16)W2[(ks * 32 + lg * 8 + j) * 64 + nt * 16 + l15];
      w2f[ks][nt] = t;
    }
  }
  float bias2[4], bias3[4];
  #pragma unroll
  for (int nt = 0; nt < 4; ++nt) { bias2[nt] = b2[nt * 16 + l15]; bias3[nt] = b3[nt * 16 + l15]; }

  _Float16* h2w = h2buf[w];
  int* vmaxw = vmaxs[w];
  #pragma unroll
  for (int q = 0; q < 8; ++q) vmaxw[lane * 8 + q] = 0;
  __syncthreads();   // only barrier: W3Ts ready

  const int g = blockIdx.x * 4 + w;   // 4096 groups
  const int n0 = g * 8;
  const int ebase = n0 * KNBR;
  #pragma unroll 1
  for (int mt = 0; mt < 5; ++mt) {
    const int e = mt * 16 + l15;
    const int m = knn[ebase + e];
    const int n = n0 + e / 10;
    const float* Up = uu + (size_t)n * 128 + lg * 8;
    const float* Vp = vv + (size_t)m * 128 + lg * 8;
    f16x8 A[4];
    #pragma unroll
    for (int ks = 0; ks < 4; ++ks) {
      float4 ua = *(const float4*)(Up + ks * 32);
      float4 ub = *(const float4*)(Up + ks * 32 + 4);
      float4 va = *(const float4*)(Vp + ks * 32);
      float4 vb = *(const float4*)(Vp + ks * 32 + 4);
      f16x8 t;
      t[0] = (_Float16)fmaxf(ua.x - va.x, 0.f);
      t[1] = (_Float16)fmaxf(ua.y - va.y, 0.f);
      t[2] = (_Float16)fmaxf(ua.z - va.z, 0.f);
      t[3] = (_Float16)fmaxf(ua.w - va.w, 0.f);
      t[4] = (_Float16)fmaxf(ub.x - vb.x, 0.f);
      t[5] = (_Float16)fmaxf(ub.y - vb.y, 0.f);
      t[6] = (_Float16)fmaxf(ub.z - vb.z, 0.f);
      t[7] = (_Float16)fmaxf(ub.w - vb.w, 0.f);
      A[ks] = t;
    }
    f32x4 acc[4];
    #pragma unroll
    for (int nt = 0; nt < 4; ++nt) { float bbv = bias2[nt]; acc[nt] = (f32x4){bbv, bbv, bbv, bbv}; }
    #pragma unroll
    for (int ks = 0; ks < 4; ++ks) {
      #pragma unroll
      for (int nt = 0; nt < 4; ++nt)
        acc[nt] = __builtin_amdgcn_mfma_f32_16x16x32_f16(A[ks], w2f[ks][nt], acc[nt], 0, 0, 0);
    }
    #pragma unroll
    for (int nt = 0; nt < 4; ++nt) {
      #pragma unroll
      for (int r = 0; r < 4; ++r)
        h2w[(lg * 4 + r) * 88 + nt * 16 + l15] = (_Float16)fmaxf(acc[nt][r], 0.f);
    }
    f16x8 A3[2];
    #pragma unroll
    for (int ks2 = 0; ks2 < 2; ++ks2)
      A3[ks2] = *(const f16x8*)(h2w + l15 * 88 + ks2 * 32 + lg * 8);
    f32x4 c3[4];
    #pragma unroll
    for (int nt = 0; nt < 4; ++nt) { float bbv = bias3[nt]; c3[nt] = (f32x4){bbv, bbv, bbv, bbv}; }
    #pragma unroll
    for (int ks2 = 0; ks2 < 2; ++ks2) {
      #pragma unroll
      for (int nt = 0; nt < 4; ++nt) {
        f16x8 bf = *(const f16x8*)(W3Ts + (nt * 16 + l15) * 72 + ks2 * 32 + lg * 8);
        c3[nt] = __builtin_amdgcn_mfma_f32_16x16x32_f16(A3[ks2], bf, c3[nt], 0, 0, 0);
      }
    }
    #pragma unroll
    for (int nt = 0; nt < 4; ++nt) {
      #pragma unroll
      for (int r = 0; r < 4; ++r) {
        float val = fmaxf(c3[nt][r], 0.f);
        int e2 = mt * 16 + lg * 4 + r;
        int p = e2 / 10;
        atomicMax(&vmaxw[p * 64 + nt * 16 + l15], __float_as_int(val));
      }
    }
  }
  {
    int p2 = lane >> 3, c0 = (lane & 7) * 8;
    const int* vp = &vmaxw[p2 * 64 + c0];
    float4 r0, r1;
    r0.x = __int_as_float(vp[0]); r0.y = __int_as_float(vp[1]);
    r0.z = __int_as_float(vp[2]); r0.w = __int_as_float(vp[3]);
    r1.x = __int_as_float(vp[4]); r1.y = __int_as_float(vp[5]);
    r1.z = __int_as_float(vp[6]); r1.w = __int_as_float(vp[7]);
    *(float4*)(vert + (size_t)(n0 + p2) * 64 + c0) = r0;
    *(float4*)(vert + (size_t)(n0 + p2) * 64 + c0 + 4) = r1;
  }
}

// ---------------- K7: global max over N per batch ----------------
__global__ void k_gmax(const float* __restrict__ vert, float* __restrict__ g) {
  __shared__ float red[4][64];
  int b = blockIdx.x >> 4, chunk = blockIdx.x & 15;
  int sub = threadIdx.x >> 6, o = threadIdx.x & 63;
  float vm = 0.f;
  for (int j = 0; j < 64; ++j) {
    int r = chunk * 256 + j * 4 + sub;
    vm = fmaxf(vm, vert[(b * NN + r) * 64 + o]);
  }
  red[sub][o] = vm;
  __syncthreads();
  if (sub == 0) {
    float mm = fmaxf(fmaxf(red[0][o], red[1][o]), fmaxf(red[2][o], red[3][o]));
    atomicMax((int*)&g[b * 64 + o], __float_as_int(mm));  // vert >= 0
  }
}

// ---------------- K7b: gb[b] = g[b] @ Wg_bottom + bg ----------------
__global__ void k_gb(const float* __restrict__ g, const float* __restrict__ Wg,
                     const float* __restrict__ bg, float* __restrict__ gb) {
  int t = threadIdx.x;        // 512
  int b = t >> 6, o = t & 63;
  float acc = bg[o];
  #pragma unroll
  for (int i = 0; i < 64; ++i)
    acc = fmaf(g[b * 64 + i], Wg[(64 + i) * 64 + o], acc);
  gb[b * 64 + o] = acc;
}

// ---------------- K8: out = relu(vert @ Wg_top + gb[b]) ----------------
__global__ void k_final(const float* __restrict__ vert, const float* __restrict__ Wg,
                        const float* __restrict__ gb, float* __restrict__ out) {
  __shared__ float Wgs[64 * 64];
  int tid = threadIdx.x, w = tid >> 6, lane = tid & 63;
  for (int i = tid; i < 4096; i += 256) Wgs[i] = Wg[i];
  __syncthreads();
  int gw = blockIdx.x * 4 + w;
  for (int j = 0; j < 4; ++j) {
    int n = gw + 8192 * j;
    int b = n >> 12;
    float vrow = vert[n * 64 + lane];
    float ac0 = gb[b * 64 + lane], ac1 = 0.f, ac2 = 0.f, ac3 = 0.f;
    #pragma unroll
    for (int i = 0; i < 64; i += 4) {
      ac0 = fmaf(__shfl(vrow, i),     Wgs[i * 64 + lane],       ac0);
      ac1 = fmaf(__shfl(vrow, i + 1), Wgs[(i + 1) * 64 + lane], ac1);
      ac2 = fmaf(__shfl(vrow, i + 2), Wgs[(i + 2) * 64 + lane], ac2);
      ac3 = fmaf(__shfl(vrow, i + 3), Wgs[(i + 3) * 64 + lane], ac3);
    }
    out[n * 64 + lane] = fmaxf((ac0 + ac1) + (ac2 + ac3), 0.f);
  }
}

extern "C" void kernel_launch(void* const* d_in, const int* in_sizes, int n_in,
                              void* d_out, int out_size, void* d_ws, size_t ws_size,
                              hipStream_t stream) {
  const float* x     = (const float*)d_in[0];
  const float* gamma = (const float*)d_in[1];
  const float* beta  = (const float*)d_in[2];
  const float* W1    = (const float*)d_in[3];
  const float* b1    = (const float*)d_in[4];
  const float* W2    = (const float*)d_in[5];
  const float* b2    = (const float*)d_in[6];
  const float* W3    = (const float*)d_in[7];
  const float* b3    = (const float*)d_in[8];
  const float* Wg    = (const float*)d_in[9];
  const float* bg    = (const float*)d_in[10];
  float* out = (float*)d_out;

  float* ws    = (float*)d_ws;
  float* stats = ws;                    // 128
  float* ss    = ws + 128;              // 128
  float* xn    = ws + 256;              // 2097152
  float* sq    = xn + 2097152;          // 32768
  int*   knn   = (int*)(sq + 32768);    // 327680 ints
  float* u     = (float*)(knn + 327680);// 4194304
  float* v     = u + 4194304;           // 4194304
  float* vert  = v + 4194304;           // 2097152
  float* g     = vert + 2097152;        // 512
  float* gb    = g + 512;               // 512
  _Float16* xh = (_Float16*)(gb + 512);             // 2097152 halfs (1 M floats)
  _Float16* xl = (_Float16*)(gb + 512 + 1048576);   // 2097152 halfs

  hipMemsetAsync(stats, 0, 128 * sizeof(float), stream);
  hipMemsetAsync(g, 0, 512 * sizeof(float), stream);

  k_bn_stats<<<256, 256, 0, stream>>>(x, stats);
  k_bn_finalize<<<1, 64, 0, stream>>>(stats, gamma, beta, ss);
  k_normalize<<<8192, 256, 0, stream>>>(x, ss, xn, sq, xh, xl);
  k_knn<<<1024, 256, 0, stream>>>(xh, xl, sq, knn);
  k_uv<<<512, 256, 0, stream>>>(xn, W1, b1, u, v);
  k_edge<<<1024, 256, 0, stream>>>(u, v, knn, W2, b2, W3, b3, vert);
  k_gmax<<<128, 256, 0, stream>>>(vert, g);
  k_gb<<<1, 512, 0, stream>>>(g, Wg, bg, gb);
  k_final<<<2048, 256, 0, stream>>>(vert, Wg, gb, out);
}

// Round 14
// 482.011 us; speedup vs baseline: 1.0226x; 1.0226x over previous
//
#include <hip/hip_runtime.h>
#include <hip/hip_fp16.h>
#include <float.h>

#define BB 8
#define NN 4096
#define DD 64
#define KNBR 10
#define ROWS (BB*NN)   // 32768

typedef _Float16 f16x8 __attribute__((ext_vector_type(8)));
typedef float f32x4 __attribute__((ext_vector_type(4)));

// ---------------- K1: BN stats (sum, sumsq per feature) ----------------
__global__ void k_bn_stats(const float* __restrict__ x, float* __restrict__ stats) {
  __shared__ float ls[2][4][64];
  int d = threadIdx.x & 63;
  int g = threadIdx.x >> 6;
  float s = 0.f, s2 = 0.f;
  for (int r = blockIdx.x * 4 + g; r < ROWS; r += gridDim.x * 4) {
    float val = x[r * 64 + d];
    s += val;
    s2 = fmaf(val, val, s2);
  }
  ls[0][g][d] = s;
  ls[1][g][d] = s2;
  __syncthreads();
  if (g == 0) {
    atomicAdd(&stats[d],      ls[0][0][d] + ls[0][1][d] + ls[0][2][d] + ls[0][3][d]);
    atomicAdd(&stats[64 + d], ls[1][0][d] + ls[1][1][d] + ls[1][2][d] + ls[1][3][d]);
  }
}

// ---------------- K2: finalize scale/shift ----------------
__global__ void k_bn_finalize(const float* __restrict__ stats,
                              const float* __restrict__ gamma,
                              const float* __restrict__ beta,
                              float* __restrict__ ss) {
  int d = threadIdx.x;  // 64 threads
  const float inv = 1.f / 32768.f;
  float mu  = stats[d] * inv;
  float var = stats[64 + d] * inv - mu * mu;
  float sc  = gamma[d] / sqrtf(var + 1e-5f);
  ss[d]      = sc;
  ss[64 + d] = beta[d] - mu * sc;
}

// ---------------- K3: normalize + row sumsq + f16 hi/lo planes ----------------
__global__ void k_normalize(const float* __restrict__ x, const float* __restrict__ ss,
                            float* __restrict__ xn, float* __restrict__ sq,
                            _Float16* __restrict__ xh, _Float16* __restrict__ xl) {
  int row = blockIdx.x * 4 + (threadIdx.x >> 6);
  int d = threadIdx.x & 63;
  int idx = row * 64 + d;
  float val = fmaf(x[idx], ss[d], ss[64 + d]);
  xn[idx] = val;
  _Float16 h = (_Float16)val;
  _Float16 l = (_Float16)(val - (float)h);
  xh[idx] = h;
  xl[idx] = l;
  float p = val * val;
  #pragma unroll
  for (int off = 32; off > 0; off >>= 1) p += __shfl_xor(p, off);
  if (d == 0) sq[row] = p;
}

// ---------------- K4: KNN halves — exact two-pass per m-half ----------------
// bid = qtile*2 + h. Block: 64 queries (A-frags in VGPRs), m-half h (2048 m),
// wave w streams 512 m in 16-m tiles (staged + sh/sl prefetch, R7 pipeline).
// True top-10 of 4096 is a subset of union of per-half exact top-10s, so:
// pass A -> half's exact 10th-smallest thr; pass B appends the half's top-10
// (dist,idx) to pairs[row][h*10..]. k_sel merges 20/row -> exact final 10.
// Grid 1024, LDS ~34 KB -> 4 blocks/CU (2x waves vs R7).
__global__ __launch_bounds__(256, 2) void k_knn_ab(const _Float16* __restrict__ xh,
                                                   const _Float16* __restrict__ xl,
                                                   const float* __restrict__ sq,
                                                   float* __restrict__ pairs,
                                                   int* __restrict__ pidx) {
  __shared__ __align__(16) char lds[33792];   // 4 waves x (2048+2048+4352)
  __shared__ float thrs[64];
  __shared__ int cnts[64];
  const int tid = threadIdx.x;
  const int w = tid >> 6, lane = tid & 63;
  const int l15 = lane & 15, lg = lane >> 4;
  const int bid = blockIdx.x;
  const int h = bid & 1;                 // m-half
  const int qb = bid >> 1;               // 0..511 query tiles
  const int b = qb >> 6;
  const int rowbase = (qb & 63) << 6;
  const int bN = b * NN;
  const _Float16* __restrict__ xhb = xh + (size_t)bN * 64;
  const _Float16* __restrict__ xlb = xl + (size_t)bN * 64;

  char* wbase = lds + w * 8448;
  char* Bhi = wbase;                    // 16 m-rows x 64 f16, XOR-swizzled
  char* Blo = wbase + 2048;
  float* Dw = (float*)(wbase + 4096);   // [64][17] floats (4352 B)

  // A fragments for the block's 64 query rows (persistent in VGPRs)
  f16x8 Ah[4][2], Al[4][2];
  #pragma unroll
  for (int mt = 0; mt < 4; ++mt) {
    #pragma unroll
    for (int ks = 0; ks < 2; ++ks) {
      int r = rowbase + mt * 16 + l15;
      Ah[mt][ks] = *(const f16x8*)(xhb + r * 64 + ks * 32 + lg * 8);
      Al[mt][ks] = *(const f16x8*)(xlb + r * 64 + ks * 32 + lg * 8);
    }
  }

  float bd[10];
  #pragma unroll
  for (int i = 0; i < 10; ++i) bd[i] = FLT_MAX;

  // staging chunk coords: 16 rows x 64 f16 = 128 chunks of 8; 2 chunks/lane
  int srow[2], scc[2];
  #pragma unroll
  for (int i = 0; i < 2; ++i) { int c = i * 64 + lane; srow[i] = c >> 3; scc[i] = c & 7; }

  const int mbase0 = h * 2048 + w * 512;
  f16x8 sh[2], sl[2];
  #pragma unroll
  for (int i = 0; i < 2; ++i) {
    sh[i] = *(const f16x8*)(xhb + (mbase0 + srow[i]) * 64 + scc[i] * 8);
    sl[i] = *(const f16x8*)(xlb + (mbase0 + srow[i]) * 64 + scc[i] * 8);
  }

  float* Drow = Dw + lane * 17;

  // ---------------- PASS A: values-only top-10 over this half ----------------
  #pragma unroll 1
  for (int t = 0; t < 32; ++t) {
    const int mb = mbase0 + t * 16;
    const int mb2 = (t < 31) ? mb + 16 : mb;
    float sqv = sq[bN + mb + l15];
    #pragma unroll
    for (int i = 0; i < 2; ++i) {
      int off = srow[i] * 128 + 16 * (scc[i] ^ (srow[i] & 7));
      *(f16x8*)(Bhi + off) = sh[i];
      *(f16x8*)(Blo + off) = sl[i];
    }
    #pragma unroll
    for (int i = 0; i < 2; ++i) {
      sh[i] = *(const f16x8*)(xhb + (mb2 + srow[i]) * 64 + scc[i] * 8);
      sl[i] = *(const f16x8*)(xlb + (mb2 + srow[i]) * 64 + scc[i] * 8);
    }
    f16x8 Bh[2], Bl[2];
    #pragma unroll
    for (int ks = 0; ks < 2; ++ks) {
      int off = l15 * 128 + 16 * ((ks * 4 + lg) ^ (l15 & 7));
      Bh[ks] = *(const f16x8*)(Bhi + off);
      Bl[ks] = *(const f16x8*)(Blo + off);
    }
    #pragma unroll
    for (int mt = 0; mt < 4; ++mt) {
      f32x4 a0 = {0.f, 0.f, 0.f, 0.f};
      #pragma unroll
      for (int ks = 0; ks < 2; ++ks) {
        a0 = __builtin_amdgcn_mfma_f32_16x16x32_f16(Ah[mt][ks], Bh[ks], a0, 0, 0, 0);
        a0 = __builtin_amdgcn_mfma_f32_16x16x32_f16(Ah[mt][ks], Bl[ks], a0, 0, 0, 0);
        a0 = __builtin_amdgcn_mfma_f32_16x16x32_f16(Al[mt][ks], Bh[ks], a0, 0, 0, 0);
      }
      int rw = mt * 16 + lg * 4;
      #pragma unroll
      for (int r2 = 0; r2 < 4; ++r2)
        Dw[(rw + r2) * 17 + l15] = fmaf(-2.f, a0[r2], sqv);
    }
    // scan 16 m's (lane = row, stride 17 -> <=2-way banks)
    #pragma unroll 4
    for (int mm = 0; mm < 16; ++mm) {
      float cd = Drow[mm];
      if (cd < bd[9]) {
        float prev = bd[0];
        bd[0] = fminf(cd, bd[0]);
        #pragma unroll
        for (int j = 1; j < 10; ++j) {
          float cur = bd[j];
          bd[j] = fminf(cur, fmaxf(prev, cd));   // -> v_med3_f32
          prev = cur;
        }
      }
    }
  }

  // ---------------- merge 4 wave-lists -> per-row half threshold ----------------
  __syncthreads();
  float* md = (float*)lds;   // [4][64][10]
  #pragma unroll
  for (int i = 0; i < 10; ++i) md[(w * 64 + lane) * 10 + i] = bd[i];
  if (tid < 64) cnts[tid] = 0;
  __syncthreads();
  if (tid < 64) {
    float fd[10];
    #pragma unroll
    for (int i = 0; i < 10; ++i) fd[i] = FLT_MAX;
    for (int w2 = 0; w2 < 4; ++w2) {
      #pragma unroll 1
      for (int kk = 0; kk < 10; ++kk) {
        float cd = md[(w2 * 64 + tid) * 10 + kk];
        if (cd < fd[9]) {
          float prev = fd[0];
          fd[0] = fminf(cd, fd[0]);
          #pragma unroll
          for (int j = 1; j < 10; ++j) {
            float cur = fd[j];
            fd[j] = fminf(cur, fmaxf(prev, cd));
            prev = cur;
          }
        } else break;   // lists sorted ascending
      }
    }
    thrs[tid] = fd[9];
  }
  __syncthreads();

  float thv[4][4];
  #pragma unroll
  for (int mt = 0; mt < 4; ++mt)
    #pragma unroll
    for (int r2 = 0; r2 < 4; ++r2)
      thv[mt][r2] = thrs[mt * 16 + lg * 4 + r2];

  float* prow = pairs + (size_t)(bN + rowbase) * 20 + h * 10;
  int*   irow = pidx  + (size_t)(bN + rowbase) * 20 + h * 10;

  // ---------------- PASS B: recompute + threshold-append (this half) ----------------
  #pragma unroll
  for (int i = 0; i < 2; ++i) {
    sh[i] = *(const f16x8*)(xhb + (mbase0 + srow[i]) * 64 + scc[i] * 8);
    sl[i] = *(const f16x8*)(xlb + (mbase0 + srow[i]) * 64 + scc[i] * 8);
  }
  #pragma unroll 1
  for (int t = 0; t < 32; ++t) {
    const int mb = mbase0 + t * 16;
    const int mb2 = (t < 31) ? mb + 16 : mb;
    float sqv = sq[bN + mb + l15];
    #pragma unroll
    for (int i = 0; i < 2; ++i) {
      int off = srow[i] * 128 + 16 * (scc[i] ^ (srow[i] & 7));
      *(f16x8*)(Bhi + off) = sh[i];
      *(f16x8*)(Blo + off) = sl[i];
    }
    #pragma unroll
    for (int i = 0; i < 2; ++i) {
      sh[i] = *(const f16x8*)(xhb + (mb2 + srow[i]) * 64 + scc[i] * 8);
      sl[i] = *(const f16x8*)(xlb + (mb2 + srow[i]) * 64 + scc[i] * 8);
    }
    f16x8 Bh[2], Bl[2];
    #pragma unroll
    for (int ks = 0; ks < 2; ++ks) {
      int off = l15 * 128 + 16 * ((ks * 4 + lg) ^ (l15 & 7));
      Bh[ks] = *(const f16x8*)(Bhi + off);
      Bl[ks] = *(const f16x8*)(Blo + off);
    }
    #pragma unroll
    for (int mt = 0; mt < 4; ++mt) {
      f32x4 a0 = {0.f, 0.f, 0.f, 0.f};
      #pragma unroll
      for (int ks = 0; ks < 2; ++ks) {
        a0 = __builtin_amdgcn_mfma_f32_16x16x32_f16(Ah[mt][ks], Bh[ks], a0, 0, 0, 0);
        a0 = __builtin_amdgcn_mfma_f32_16x16x32_f16(Ah[mt][ks], Bl[ks], a0, 0, 0, 0);
        a0 = __builtin_amdgcn_mfma_f32_16x16x32_f16(Al[mt][ks], Bh[ks], a0, 0, 0, 0);
      }
      #pragma unroll
      for (int r2 = 0; r2 < 4; ++r2) {
        float d0 = fmaf(-2.f, a0[r2], sqv);
        int row = mt * 16 + lg * 4 + r2;
        if (d0 <= thv[mt][r2]) {
          int slot = atomicAdd(&cnts[row], 1);
          if (slot < KNBR) {
            prow[row * 20 + slot] = d0;
            irow[row * 20 + slot] = bN + mb + l15;
          }
        }
      }
    }
  }
}

// ---------------- K4c: merge 20 candidates/row -> exact top-10 indices ----------------
__global__ void k_sel(const float* __restrict__ pairs, const int* __restrict__ pidx,
                      int* __restrict__ knn) {
  int gid = blockIdx.x * 256 + threadIdx.x;   // grid 128 -> 32768 rows
  const float* pd = pairs + (size_t)gid * 20;
  const int*   pi = pidx  + (size_t)gid * 20;
  float fd[10]; int fi[10];
  #pragma unroll
  for (int i = 0; i < 10; ++i) { fd[i] = FLT_MAX; fi[i] = 0; }
  #pragma unroll 1
  for (int k = 0; k < 20; ++k) {
    float cd = pd[k]; int ci = pi[k];
    if (cd < fd[9]) {
      #pragma unroll
      for (int j = 0; j < 10; ++j) {
        bool swp = cd < fd[j];
        float tf = fd[j]; int ti = fi[j];
        fd[j] = swp ? cd : tf; fi[j] = swp ? ci : ti;
        cd = swp ? tf : cd;    ci = swp ? ti : ci;
      }
    }
  }
  #pragma unroll
  for (int k = 0; k < 10; ++k) knn[(size_t)gid * KNBR + k] = fi[k];
}

// ---------------- K5: U/V precompute (layer-1 folded per point) ----------------
__global__ void k_uv(const float* __restrict__ xn, const float* __restrict__ W1,
                     const float* __restrict__ b1, float* __restrict__ u,
                     float* __restrict__ v) {
  __shared__ float xs[64 * 64];   // 16 KB
  const int tid = threadIdx.x;
  const int o = tid & 127;
  const bool isU = tid < 128;
  const int rowbase = blockIdx.x * 64;

  float wreg[64];
  #pragma unroll
  for (int d = 0; d < 64; ++d) {
    float bw = W1[(64 + d) * 128 + o];
    wreg[d] = isU ? (W1[d * 128 + o] + bw) : bw;
  }
  const float bb = isU ? b1[o] : 0.f;
  float* __restrict__ dst = isU ? u : v;

  {
    const float4* s4 = (const float4*)(xn + rowbase * 64);
    float4* d4 = (float4*)xs;
    #pragma unroll
    for (int i = 0; i < 4; ++i) d4[tid + 256 * i] = s4[tid + 256 * i];
  }
  __syncthreads();

  for (int r = 0; r < 64; ++r) {
    const float4* xr = (const float4*)(xs + r * 64);
    float a0 = bb, a1 = 0.f, a2 = 0.f, a3 = 0.f;
    #pragma unroll
    for (int q = 0; q < 16; ++q) {
      float4 xv = xr[q];
      a0 = fmaf(xv.x, wreg[4 * q + 0], a0);
      a1 = fmaf(xv.y, wreg[4 * q + 1], a1);
      a2 = fmaf(xv.z, wreg[4 * q + 2], a2);
      a3 = fmaf(xv.w, wreg[4 * q + 3], a3);
    }
    dst[(rowbase + r) * 128 + o] = (a0 + a1) + (a2 + a3);
  }
}

// ---------------- K6: edge MLP via MFMA, barrier-free per-wave ----------------
__global__ __launch_bounds__(256, 2) void k_edge(const float* __restrict__ uu,
                                                 const float* __restrict__ vv,
                                                 const int* __restrict__ knn,
                                                 const float* __restrict__ W2,
                                                 const float* __restrict__ b2,
                                                 const float* __restrict__ W3,
                                                 const float* __restrict__ b3,
                                                 float* __restrict__ vert) {
  __shared__ __align__(16) _Float16 W3Ts[64 * 72];        // W3T[out][k2], 9216 B
  __shared__ __align__(16) _Float16 h2buf[4][16 * 88];    // per-wave, 2816 B each
  __shared__ int vmaxs[4][512];                           // per-wave [8 pts][64]
  const int tid = threadIdx.x;
  const int w = tid >> 6, lane = tid & 63;
  const int l15 = lane & 15, lg = lane >> 4;

  for (int i = tid; i < 64 * 64; i += 256) {
    int o3 = i >> 6, k2 = i & 63;
    W3Ts[o3 * 72 + k2] = (_Float16)W3[k2 * 64 + o3];
  }
  f16x8 w2f[4][4];
  #pragma unroll
  for (int ks = 0; ks < 4; ++ks) {
    #pragma unroll
    for (int nt = 0; nt < 4; ++nt) {
      f16x8 t;
      #pragma unroll
      for (int j = 0; j < 8; ++j)
        t[j] = (_Float16)W2[(ks * 32 + lg * 8 + j) * 64 + nt * 16 + l15];
      w2f[ks][nt] = t;
    }
  }
  float bias2[4], bias3[4];
  #pragma unroll
  for (int nt = 0; nt < 4; ++nt) { bias2[nt] = b2[nt * 16 + l15]; bias3[nt] = b3[nt * 16 + l15]; }

  _Float16* h2w = h2buf[w];
  int* vmaxw = vmaxs[w];
  #pragma unroll
  for (int q = 0; q < 8; ++q) vmaxw[lane * 8 + q] = 0;
  __syncthreads();   // only barrier: W3Ts ready

  const int g = blockIdx.x * 4 + w;   // 4096 groups
  const int n0 = g * 8;
  const int ebase = n0 * KNBR;
  #pragma unroll 1
  for (int mt = 0; mt < 5; ++mt) {
    const int e = mt * 16 + l15;
    const int m = knn[ebase + e];
    const int n = n0 + e / 10;
    const float* Up = uu + (size_t)n * 128 + lg * 8;
    const float* Vp = vv + (size_t)m * 128 + lg * 8;
    f16x8 A[4];
    #pragma unroll
    for (int ks = 0; ks < 4; ++ks) {
      float4 ua = *(const float4*)(Up + ks * 32);
      float4 ub = *(const float4*)(Up + ks * 32 + 4);
      float4 va = *(const float4*)(Vp + ks * 32);
      float4 vb = *(const float4*)(Vp + ks * 32 + 4);
      f16x8 t;
      t[0] = (_Float16)fmaxf(ua.x - va.x, 0.f);
      t[1] = (_Float16)fmaxf(ua.y - va.y, 0.f);
      t[2] = (_Float16)fmaxf(ua.z - va.z, 0.f);
      t[3] = (_Float16)fmaxf(ua.w - va.w, 0.f);
      t[4] = (_Float16)fmaxf(ub.x - vb.x, 0.f);
      t[5] = (_Float16)fmaxf(ub.y - vb.y, 0.f);
      t[6] = (_Float16)fmaxf(ub.z - vb.z, 0.f);
      t[7] = (_Float16)fmaxf(ub.w - vb.w, 0.f);
      A[ks] = t;
    }
    f32x4 acc[4];
    #pragma unroll
    for (int nt = 0; nt < 4; ++nt) { float bbv = bias2[nt]; acc[nt] = (f32x4){bbv, bbv, bbv, bbv}; }
    #pragma unroll
    for (int ks = 0; ks < 4; ++ks) {
      #pragma unroll
      for (int nt = 0; nt < 4; ++nt)
        acc[nt] = __builtin_amdgcn_mfma_f32_16x16x32_f16(A[ks], w2f[ks][nt], acc[nt], 0, 0, 0);
    }
    #pragma unroll
    for (int nt = 0; nt < 4; ++nt) {
      #pragma unroll
      for (int r = 0; r < 4; ++r)
        h2w[(lg * 4 + r) * 88 + nt * 16 + l15] = (_Float16)fmaxf(acc[nt][r], 0.f);
    }
    f16x8 A3[2];
    #pragma unroll
    for (int ks2 = 0; ks2 < 2; ++ks2)
      A3[ks2] = *(const f16x8*)(h2w + l15 * 88 + ks2 * 32 + lg * 8);
    f32x4 c3[4];
    #pragma unroll
    for (int nt = 0; nt < 4; ++nt) { float bbv = bias3[nt]; c3[nt] = (f32x4){bbv, bbv, bbv, bbv}; }
    #pragma unroll
    for (int ks2 = 0; ks2 < 2; ++ks2) {
      #pragma unroll
      for (int nt = 0; nt < 4; ++nt) {
        f16x8 bf = *(const f16x8*)(W3Ts + (nt * 16 + l15) * 72 + ks2 * 32 + lg * 8);
        c3[nt] = __builtin_amdgcn_mfma_f32_16x16x32_f16(A3[ks2], bf, c3[nt], 0, 0, 0);
      }
    }
    #pragma unroll
    for (int nt = 0; nt < 4; ++nt) {
      #pragma unroll
      for (int r = 0; r < 4; ++r) {
        float val = fmaxf(c3[nt][r], 0.f);
        int e2 = mt * 16 + lg * 4 + r;
        int p = e2 / 10;
        atomicMax(&vmaxw[p * 64 + nt * 16 + l15], __float_as_int(val));
      }
    }
  }
  {
    int p2 = lane >> 3, c0 = (lane & 7) * 8;
    const int* vp = &vmaxw[p2 * 64 + c0];
    float4 r0, r1;
    r0.x = __int_as_float(vp[0]); r0.y = __int_as_float(vp[1]);
    r0.z = __int_as_float(vp[2]); r0.w = __int_as_float(vp[3]);
    r1.x = __int_as_float(vp[4]); r1.y = __int_as_float(vp[5]);
    r1.z = __int_as_float(vp[6]); r1.w = __int_as_float(vp[7]);
    *(float4*)(vert + (size_t)(n0 + p2) * 64 + c0) = r0;
    *(float4*)(vert + (size_t)(n0 + p2) * 64 + c0 + 4) = r1;
  }
}

// ---------------- K7: global max over N per batch ----------------
__global__ void k_gmax(const float* __restrict__ vert, float* __restrict__ g) {
  __shared__ float red[4][64];
  int b = blockIdx.x >> 4, chunk = blockIdx.x & 15;
  int sub = threadIdx.x >> 6, o = threadIdx.x & 63;
  float vm = 0.f;
  for (int j = 0; j < 64; ++j) {
    int r = chunk * 256 + j * 4 + sub;
    vm = fmaxf(vm, vert[(b * NN + r) * 64 + o]);
  }
  red[sub][o] = vm;
  __syncthreads();
  if (sub == 0) {
    float mm = fmaxf(fmaxf(red[0][o], red[1][o]), fmaxf(red[2][o], red[3][o]));
    atomicMax((int*)&g[b * 64 + o], __float_as_int(mm));  // vert >= 0
  }
}

// ---------------- K7b: gb[b] = g[b] @ Wg_bottom + bg ----------------
__global__ void k_gb(const float* __restrict__ g, const float* __restrict__ Wg,
                     const float* __restrict__ bg, float* __restrict__ gb) {
  int t = threadIdx.x;        // 512
  int b = t >> 6, o = t & 63;
  float acc = bg[o];
  #pragma unroll
  for (int i = 0; i < 64; ++i)
    acc = fmaf(g[b * 64 + i], Wg[(64 + i) * 64 + o], acc);
  gb[b * 64 + o] = acc;
}

// ---------------- K8: out = relu(vert @ Wg_top + gb[b]) ----------------
__global__ void k_final(const float* __restrict__ vert, const float* __restrict__ Wg,
                        const float* __restrict__ gb, float* __restrict__ out) {
  __shared__ float Wgs[64 * 64];
  int tid = threadIdx.x, w = tid >> 6, lane = tid & 63;
  for (int i = tid; i < 4096; i += 256) Wgs[i] = Wg[i];
  __syncthreads();
  int gw = blockIdx.x * 4 + w;
  for (int j = 0; j < 4; ++j) {
    int n = gw + 8192 * j;
    int b = n >> 12;
    float vrow = vert[n * 64 + lane];
    float ac0 = gb[b * 64 + lane], ac1 = 0.f, ac2 = 0.f, ac3 = 0.f;
    #pragma unroll
    for (int i = 0; i < 64; i += 4) {
      ac0 = fmaf(__shfl(vrow, i),     Wgs[i * 64 + lane],       ac0);
      ac1 = fmaf(__shfl(vrow, i + 1), Wgs[(i + 1) * 64 + lane], ac1);
      ac2 = fmaf(__shfl(vrow, i + 2), Wgs[(i + 2) * 64 + lane], ac2);
      ac3 = fmaf(__shfl(vrow, i + 3), Wgs[(i + 3) * 64 + lane], ac3);
    }
    out[n * 64 + lane] = fmaxf((ac0 + ac1) + (ac2 + ac3), 0.f);
  }
}

extern "C" void kernel_launch(void* const* d_in, const int* in_sizes, int n_in,
                              void* d_out, int out_size, void* d_ws, size_t ws_size,
                              hipStream_t stream) {
  const float* x     = (const float*)d_in[0];
  const float* gamma = (const float*)d_in[1];
  const float* beta  = (const float*)d_in[2];
  const float* W1    = (const float*)d_in[3];
  const float* b1    = (const float*)d_in[4];
  const float* W2    = (const float*)d_in[5];
  const float* b2    = (const float*)d_in[6];
  const float* W3    = (const float*)d_in[7];
  const float* b3    = (const float*)d_in[8];
  const float* Wg    = (const float*)d_in[9];
  const float* bg    = (const float*)d_in[10];
  float* out = (float*)d_out;

  float* ws    = (float*)d_ws;
  float* stats = ws;                    // 128
  float* ss    = ws + 128;              // 128
  float* xn    = ws + 256;              // 2097152
  float* sq    = xn + 2097152;          // 32768
  int*   knn   = (int*)(sq + 32768);    // 327680 ints
  float* u     = (float*)(knn + 327680);// 4194304
  float* v     = u + 4194304;           // 4194304
  float* vert  = v + 4194304;           // 2097152
  float* g     = vert + 2097152;        // 512
  float* gb    = g + 512;               // 512
  _Float16* xh = (_Float16*)(gb + 512);             // 2097152 halfs (1 M floats)
  _Float16* xl = (_Float16*)(gb + 512 + 1048576);   // 2097152 halfs

  // knn candidate buffers alias u (k_uv writes u AFTER k_sel reads)
  float* pairs = u;                         // 32768*20 floats = 655360
  int*   pidx  = (int*)(u + 655360);        // 655360 ints

  hipMemsetAsync(stats, 0, 128 * sizeof(float), stream);
  hipMemsetAsync(g, 0, 512 * sizeof(float), stream);

  k_bn_stats<<<256, 256, 0, stream>>>(x, stats);
  k_bn_finalize<<<1, 64, 0, stream>>>(stats, gamma, beta, ss);
  k_normalize<<<8192, 256, 0, stream>>>(x, ss, xn, sq, xh, xl);
  k_knn_ab<<<1024, 256, 0, stream>>>(xh, xl, sq, pairs, pidx);
  k_sel<<<128, 256, 0, stream>>>(pairs, pidx, knn);
  k_uv<<<512, 256, 0, stream>>>(xn, W1, b1, u, v);
  k_edge<<<1024, 256, 0, stream>>>(u, v, knn, W2, b2, W3, b3, vert);
  k_gmax<<<128, 256, 0, stream>>>(vert, g);
  k_gb<<<1, 512, 0, stream>>>(g, Wg, bg, gb);
  k_final<<<2048, 256, 0, stream>>>(vert, Wg, gb, out);
}

// Round 15
// 459.697 us; speedup vs baseline: 1.0722x; 1.0485x over previous
//
#include <hip/hip_runtime.h>
#include <hip/hip_fp16.h>
#include <float.h>

#define BB 8
#define NN 4096
#define DD 64
#define KNBR 10
#define ROWS (BB*NN)   // 32768

typedef _Float16 f16x8 __attribute__((ext_vector_type(8)));
typedef float f32x4 __attribute__((ext_vector_type(4)));

// ---------------- K1: BN stats (sum, sumsq per feature) ----------------
__global__ void k_bn_stats(const float* __restrict__ x, float* __restrict__ stats) {
  __shared__ float ls[2][4][64];
  int d = threadIdx.x & 63;
  int g = threadIdx.x >> 6;
  float s = 0.f, s2 = 0.f;
  for (int r = blockIdx.x * 4 + g; r < ROWS; r += gridDim.x * 4) {
    float val = x[r * 64 + d];
    s += val;
    s2 = fmaf(val, val, s2);
  }
  ls[0][g][d] = s;
  ls[1][g][d] = s2;
  __syncthreads();
  if (g == 0) {
    atomicAdd(&stats[d],      ls[0][0][d] + ls[0][1][d] + ls[0][2][d] + ls[0][3][d]);
    atomicAdd(&stats[64 + d], ls[1][0][d] + ls[1][1][d] + ls[1][2][d] + ls[1][3][d]);
  }
}

// ---------------- K2: finalize scale/shift ----------------
__global__ void k_bn_finalize(const float* __restrict__ stats,
                              const float* __restrict__ gamma,
                              const float* __restrict__ beta,
                              float* __restrict__ ss) {
  int d = threadIdx.x;  // 64 threads
  const float inv = 1.f / 32768.f;
  float mu  = stats[d] * inv;
  float var = stats[64 + d] * inv - mu * mu;
  float sc  = gamma[d] / sqrtf(var + 1e-5f);
  ss[d]      = sc;
  ss[64 + d] = beta[d] - mu * sc;
}

// ---------------- K3: normalize + row sumsq + f16 hi/lo planes ----------------
__global__ void k_normalize(const float* __restrict__ x, const float* __restrict__ ss,
                            float* __restrict__ xn, float* __restrict__ sq,
                            _Float16* __restrict__ xh, _Float16* __restrict__ xl) {
  int row = blockIdx.x * 4 + (threadIdx.x >> 6);
  int d = threadIdx.x & 63;
  int idx = row * 64 + d;
  float val = fmaf(x[idx], ss[d], ss[64 + d]);
  xn[idx] = val;
  _Float16 h = (_Float16)val;
  _Float16 l = (_Float16)(val - (float)h);
  xh[idx] = h;
  xl[idx] = l;
  float p = val * val;
  #pragma unroll
  for (int off = 32; off > 0; off >>= 1) p += __shfl_xor(p, off);
  if (d == 0) sq[row] = p;
}

// ---------------- K4: KNN, exact two-pass (round-7 kernel, measured 231us) ----------------
__global__ __launch_bounds__(256, 2) void k_knn(const _Float16* __restrict__ xh,
                                                const _Float16* __restrict__ xl,
                                                const float* __restrict__ sq,
                                                int* __restrict__ knn) {
  __shared__ __align__(16) float lds[16640];   // 66560 B = 4 waves x 16640 B
  __shared__ float thrs[64];
  __shared__ int cnts[64];
  const int tid = threadIdx.x;
  const int w = tid >> 6, lane = tid & 63;
  const int l15 = lane & 15, lg = lane >> 4;
  const int b = blockIdx.x >> 6;
  const int rowbase = (blockIdx.x & 63) << 6;
  const int bN = b * NN;
  const _Float16* __restrict__ xhb = xh + (size_t)bN * 64;
  const _Float16* __restrict__ xlb = xl + (size_t)bN * 64;

  char* wbase = (char*)lds + w * 16640;
  char* Bhi = wbase;                    // 32 rows x 64 f16, XOR-swizzled (4096 B)
  char* Blo = wbase + 4096;             // 4096 B
  float* Dw = (float*)(wbase + 8192);   // [64][33] floats (8448 B)

  f16x8 Ah[4][2], Al[4][2];
  #pragma unroll
  for (int mt = 0; mt < 4; ++mt) {
    #pragma unroll
    for (int ks = 0; ks < 2; ++ks) {
      int r = rowbase + mt * 16 + l15;
      Ah[mt][ks] = *(const f16x8*)(xhb + r * 64 + ks * 32 + lg * 8);
      Al[mt][ks] = *(const f16x8*)(xlb + r * 64 + ks * 32 + lg * 8);
    }
  }

  float bd[10];
  #pragma unroll
  for (int i = 0; i < 10; ++i) bd[i] = FLT_MAX;

  int srow[4], scc[4];
  #pragma unroll
  for (int i = 0; i < 4; ++i) { int c = i * 64 + lane; srow[i] = c >> 3; scc[i] = c & 7; }

  f16x8 sh[4], sl[4];
  {
    int mb0 = w * 32;
    #pragma unroll
    for (int i = 0; i < 4; ++i) {
      sh[i] = *(const f16x8*)(xhb + (mb0 + srow[i]) * 64 + scc[i] * 8);
      sl[i] = *(const f16x8*)(xlb + (mb0 + srow[i]) * 64 + scc[i] * 8);
    }
  }

  float* Drow = Dw + lane * 33;

  // ---------------- PASS A: values-only top-10 ----------------
  #pragma unroll 1
  for (int t = 0; t < 32; ++t) {
    const int mb = (t * 4 + w) * 32;
    const int mb2 = (t < 31) ? ((t + 1) * 4 + w) * 32 : mb;
    float sqv0 = sq[bN + mb + l15];
    float sqv1 = sq[bN + mb + 16 + l15];
    #pragma unroll
    for (int i = 0; i < 4; ++i) {
      int off = srow[i] * 128 + 16 * (scc[i] ^ (srow[i] & 7));
      *(f16x8*)(Bhi + off) = sh[i];
      *(f16x8*)(Blo + off) = sl[i];
    }
    #pragma unroll
    for (int i = 0; i < 4; ++i) {
      sh[i] = *(const f16x8*)(xhb + (mb2 + srow[i]) * 64 + scc[i] * 8);
      sl[i] = *(const f16x8*)(xlb + (mb2 + srow[i]) * 64 + scc[i] * 8);
    }
    f16x8 Bh[2][2], Bl[2][2];
    #pragma unroll
    for (int nt = 0; nt < 2; ++nt) {
      #pragma unroll
      for (int ks = 0; ks < 2; ++ks) {
        int rr2 = nt * 16 + l15;
        int off = rr2 * 128 + 16 * ((ks * 4 + lg) ^ (rr2 & 7));
        Bh[nt][ks] = *(const f16x8*)(Bhi + off);
        Bl[nt][ks] = *(const f16x8*)(Blo + off);
      }
    }
    #pragma unroll
    for (int mt = 0; mt < 4; ++mt) {
      f32x4 a0 = {0.f, 0.f, 0.f, 0.f}, a1 = {0.f, 0.f, 0.f, 0.f};
      #pragma unroll
      for (int ks = 0; ks < 2; ++ks) {
        a0 = __builtin_amdgcn_mfma_f32_16x16x32_f16(Ah[mt][ks], Bh[0][ks], a0, 0, 0, 0);
        a1 = __builtin_amdgcn_mfma_f32_16x16x32_f16(Ah[mt][ks], Bh[1][ks], a1, 0, 0, 0);
        a0 = __builtin_amdgcn_mfma_f32_16x16x32_f16(Ah[mt][ks], Bl[0][ks], a0, 0, 0, 0);
        a1 = __builtin_amdgcn_mfma_f32_16x16x32_f16(Ah[mt][ks], Bl[1][ks], a1, 0, 0, 0);
        a0 = __builtin_amdgcn_mfma_f32_16x16x32_f16(Al[mt][ks], Bh[0][ks], a0, 0, 0, 0);
        a1 = __builtin_amdgcn_mfma_f32_16x16x32_f16(Al[mt][ks], Bh[1][ks], a1, 0, 0, 0);
      }
      int rw = mt * 16 + lg * 4;
      #pragma unroll
      for (int r2 = 0; r2 < 4; ++r2) {
        Dw[(rw + r2) * 33 + l15]      = fmaf(-2.f, a0[r2], sqv0);
        Dw[(rw + r2) * 33 + 16 + l15] = fmaf(-2.f, a1[r2], sqv1);
      }
    }
    #pragma unroll 4
    for (int mm = 0; mm < 32; ++mm) {
      float cd = Drow[mm];
      if (cd < bd[9]) {
        float prev = bd[0];
        bd[0] = fminf(cd, bd[0]);
        #pragma unroll
        for (int j = 1; j < 10; ++j) {
          float cur = bd[j];
          bd[j] = fminf(cur, fmaxf(prev, cd));
          prev = cur;
        }
      }
    }
  }

  // ---------------- merge -> per-row exact 10th-smallest threshold ----------------
  __syncthreads();
  float* md = lds;                   // [4][64][10] dists
  #pragma unroll
  for (int i = 0; i < 10; ++i) md[(w * 64 + lane) * 10 + i] = bd[i];
  if (tid < 64) cnts[tid] = 0;
  __syncthreads();
  if (tid < 64) {
    float fd[10];
    #pragma unroll
    for (int i = 0; i < 10; ++i) fd[i] = FLT_MAX;
    for (int w2 = 0; w2 < 4; ++w2) {
      #pragma unroll
      for (int kk = 0; kk < 10; ++kk) {
        float cd = md[(w2 * 64 + tid) * 10 + kk];
        if (cd < fd[9]) {
          float prev = fd[0];
          fd[0] = fminf(cd, fd[0]);
          #pragma unroll
          for (int j = 1; j < 10; ++j) {
            float cur = fd[j];
            fd[j] = fminf(cur, fmaxf(prev, cd));
            prev = cur;
          }
        }
      }
    }
    thrs[tid] = fd[9];
  }
  __syncthreads();

  float thv[4][4];
  #pragma unroll
  for (int mt = 0; mt < 4; ++mt)
    #pragma unroll
    for (int r2 = 0; r2 < 4; ++r2)
      thv[mt][r2] = thrs[mt * 16 + lg * 4 + r2];

  int* knnrow = knn + (size_t)(bN + rowbase) * KNBR;

  // ---------------- PASS B: recompute + threshold-append ----------------
  {
    int mb0 = w * 32;
    #pragma unroll
    for (int i = 0; i < 4; ++i) {
      sh[i] = *(const f16x8*)(xhb + (mb0 + srow[i]) * 64 + scc[i] * 8);
      sl[i] = *(const f16x8*)(xlb + (mb0 + srow[i]) * 64 + scc[i] * 8);
    }
  }
  #pragma unroll 1
  for (int t = 0; t < 32; ++t) {
    const int mb = (t * 4 + w) * 32;
    const int mb2 = (t < 31) ? ((t + 1) * 4 + w) * 32 : mb;
    float sqv0 = sq[bN + mb + l15];
    float sqv1 = sq[bN + mb + 16 + l15];
    #pragma unroll
    for (int i = 0; i < 4; ++i) {
      int off = srow[i] * 128 + 16 * (scc[i] ^ (srow[i] & 7));
      *(f16x8*)(Bhi + off) = sh[i];
      *(f16x8*)(Blo + off) = sl[i];
    }
    #pragma unroll
    for (int i = 0; i < 4; ++i) {
      sh[i] = *(const f16x8*)(xhb + (mb2 + srow[i]) * 64 + scc[i] * 8);
      sl[i] = *(const f16x8*)(xlb + (mb2 + srow[i]) * 64 + scc[i] * 8);
    }
    f16x8 Bh[2][2], Bl[2][2];
    #pragma unroll
    for (int nt = 0; nt < 2; ++nt) {
      #pragma unroll
      for (int ks = 0; ks < 2; ++ks) {
        int rr2 = nt * 16 + l15;
        int off = rr2 * 128 + 16 * ((ks * 4 + lg) ^ (rr2 & 7));
        Bh[nt][ks] = *(const f16x8*)(Bhi + off);
        Bl[nt][ks] = *(const f16x8*)(Blo + off);
      }
    }
    #pragma unroll
    for (int mt = 0; mt < 4; ++mt) {
      f32x4 a0 = {0.f, 0.f, 0.f, 0.f}, a1 = {0.f, 0.f, 0.f, 0.f};
      #pragma unroll
      for (int ks = 0; ks < 2; ++ks) {
        a0 = __builtin_amdgcn_mfma_f32_16x16x32_f16(Ah[mt][ks], Bh[0][ks], a0, 0, 0, 0);
        a1 = __builtin_amdgcn_mfma_f32_16x16x32_f16(Ah[mt][ks], Bh[1][ks], a1, 0, 0, 0);
        a0 = __builtin_amdgcn_mfma_f32_16x16x32_f16(Ah[mt][ks], Bl[0][ks], a0, 0, 0, 0);
        a1 = __builtin_amdgcn_mfma_f32_16x16x32_f16(Ah[mt][ks], Bl[1][ks], a1, 0, 0, 0);
        a0 = __builtin_amdgcn_mfma_f32_16x16x32_f16(Al[mt][ks], Bh[0][ks], a0, 0, 0, 0);
        a1 = __builtin_amdgcn_mfma_f32_16x16x32_f16(Al[mt][ks], Bh[1][ks], a1, 0, 0, 0);
      }
      #pragma unroll
      for (int r2 = 0; r2 < 4; ++r2) {
        float d0 = fmaf(-2.f, a0[r2], sqv0);
        float d1 = fmaf(-2.f, a1[r2], sqv1);
        int row = mt * 16 + lg * 4 + r2;
        if (d0 <= thv[mt][r2]) {
          int slot = atomicAdd(&cnts[row], 1);
          if (slot < KNBR) knnrow[row * KNBR + slot] = bN + mb + l15;
        }
        if (d1 <= thv[mt][r2]) {
          int slot = atomicAdd(&cnts[row], 1);
          if (slot < KNBR) knnrow[row * KNBR + slot] = bN + mb + 16 + l15;
        }
      }
    }
  }
}

// ---------------- K5: U/V precompute -> f16 output (halves k_edge gather bytes) ----------------
__global__ void k_uv(const float* __restrict__ xn, const float* __restrict__ W1,
                     const float* __restrict__ b1, _Float16* __restrict__ u,
                     _Float16* __restrict__ v) {
  __shared__ float xs[64 * 64];   // 16 KB
  const int tid = threadIdx.x;
  const int o = tid & 127;
  const bool isU = tid < 128;
  const int rowbase = blockIdx.x * 64;

  float wreg[64];
  #pragma unroll
  for (int d = 0; d < 64; ++d) {
    float bw = W1[(64 + d) * 128 + o];
    wreg[d] = isU ? (W1[d * 128 + o] + bw) : bw;
  }
  const float bb = isU ? b1[o] : 0.f;
  _Float16* __restrict__ dst = isU ? u : v;

  {
    const float4* s4 = (const float4*)(xn + rowbase * 64);
    float4* d4 = (float4*)xs;
    #pragma unroll
    for (int i = 0; i < 4; ++i) d4[tid + 256 * i] = s4[tid + 256 * i];
  }
  __syncthreads();

  for (int r = 0; r < 64; ++r) {
    const float4* xr = (const float4*)(xs + r * 64);
    float a0 = bb, a1 = 0.f, a2 = 0.f, a3 = 0.f;
    #pragma unroll
    for (int q = 0; q < 16; ++q) {
      float4 xv = xr[q];
      a0 = fmaf(xv.x, wreg[4 * q + 0], a0);
      a1 = fmaf(xv.y, wreg[4 * q + 1], a1);
      a2 = fmaf(xv.z, wreg[4 * q + 2], a2);
      a3 = fmaf(xv.w, wreg[4 * q + 3], a3);
    }
    dst[(rowbase + r) * 128 + o] = (_Float16)((a0 + a1) + (a2 + a3));
  }
}

// ---------------- K6: edge MLP via MFMA; f16 U/V gathers + packed h1 ----------------
__global__ __launch_bounds__(256, 2) void k_edge(const _Float16* __restrict__ uu,
                                                 const _Float16* __restrict__ vv,
                                                 const int* __restrict__ knn,
                                                 const float* __restrict__ W2,
                                                 const float* __restrict__ b2,
                                                 const float* __restrict__ W3,
                                                 const float* __restrict__ b3,
                                                 float* __restrict__ vert) {
  __shared__ __align__(16) _Float16 W3Ts[64 * 72];        // W3T[out][k2], 9216 B
  __shared__ __align__(16) _Float16 h2buf[4][16 * 88];    // per-wave, 2816 B each
  __shared__ int vmaxs[4][512];                           // per-wave [8 pts][64]
  const int tid = threadIdx.x;
  const int w = tid >> 6, lane = tid & 63;
  const int l15 = lane & 15, lg = lane >> 4;

  for (int i = tid; i < 64 * 64; i += 256) {
    int o3 = i >> 6, k2 = i & 63;
    W3Ts[o3 * 72 + k2] = (_Float16)W3[k2 * 64 + o3];
  }
  f16x8 w2f[4][4];
  #pragma unroll
  for (int ks = 0; ks < 4; ++ks) {
    #pragma unroll
    for (int nt = 0; nt < 4; ++nt) {
      f16x8 t;
      #pragma unroll
      for (int j = 0; j < 8; ++j)
        t[j] = (_Float16)W2[(ks * 32 + lg * 8 + j) * 64 + nt * 16 + l15];
      w2f[ks][nt] = t;
    }
  }
  float bias2[4], bias3[4];
  #pragma unroll
  for (int nt = 0; nt < 4; ++nt) { bias2[nt] = b2[nt * 16 + l15]; bias3[nt] = b3[nt * 16 + l15]; }

  _Float16* h2w = h2buf[w];
  int* vmaxw = vmaxs[w];
  #pragma unroll
  for (int q = 0; q < 8; ++q) vmaxw[lane * 8 + q] = 0;
  __syncthreads();   // only barrier: W3Ts ready

  const int g = blockIdx.x * 4 + w;   // 4096 groups
  const int n0 = g * 8;
  const int ebase = n0 * KNBR;
  #pragma unroll 1
  for (int mt = 0; mt < 5; ++mt) {
    const int e = mt * 16 + l15;
    const int m = knn[ebase + e];
    const int n = n0 + e / 10;
    const _Float16* Up = uu + (size_t)n * 128 + lg * 8;
    const _Float16* Vp = vv + (size_t)m * 128 + lg * 8;
    f16x8 A[4];
    #pragma unroll
    for (int ks = 0; ks < 4; ++ks) {
      f16x8 ud = *(const f16x8*)(Up + ks * 32);
      f16x8 vd = *(const f16x8*)(Vp + ks * 32);
      f16x8 df = ud - vd;                 // v_pk_sub_f16
      f16x8 t;
      #pragma unroll
      for (int j = 0; j < 8; ++j)
        t[j] = df[j] > (_Float16)0.f ? df[j] : (_Float16)0.f;  // v_pk_max_f16
      A[ks] = t;
    }
    f32x4 acc[4];
    #pragma unroll
    for (int nt = 0; nt < 4; ++nt) { float bbv = bias2[nt]; acc[nt] = (f32x4){bbv, bbv, bbv, bbv}; }
    #pragma unroll
    for (int ks = 0; ks < 4; ++ks) {
      #pragma unroll
      for (int nt = 0; nt < 4; ++nt)
        acc[nt] = __builtin_amdgcn_mfma_f32_16x16x32_f16(A[ks], w2f[ks][nt], acc[nt], 0, 0, 0);
    }
    #pragma unroll
    for (int nt = 0; nt < 4; ++nt) {
      #pragma unroll
      for (int r = 0; r < 4; ++r)
        h2w[(lg * 4 + r) * 88 + nt * 16 + l15] = (_Float16)fmaxf(acc[nt][r], 0.f);
    }
    f16x8 A3[2];
    #pragma unroll
    for (int ks2 = 0; ks2 < 2; ++ks2)
      A3[ks2] = *(const f16x8*)(h2w + l15 * 88 + ks2 * 32 + lg * 8);
    f32x4 c3[4];
    #pragma unroll
    for (int nt = 0; nt < 4; ++nt) { float bbv = bias3[nt]; c3[nt] = (f32x4){bbv, bbv, bbv, bbv}; }
    #pragma unroll
    for (int ks2 = 0; ks2 < 2; ++ks2) {
      #pragma unroll
      for (int nt = 0; nt < 4; ++nt) {
        f16x8 bf = *(const f16x8*)(W3Ts + (nt * 16 + l15) * 72 + ks2 * 32 + lg * 8);
        c3[nt] = __builtin_amdgcn_mfma_f32_16x16x32_f16(A3[ks2], bf, c3[nt], 0, 0, 0);
      }
    }
    #pragma unroll
    for (int nt = 0; nt < 4; ++nt) {
      #pragma unroll
      for (int r = 0; r < 4; ++r) {
        float val = fmaxf(c3[nt][r], 0.f);
        int e2 = mt * 16 + lg * 4 + r;
        int p = e2 / 10;
        atomicMax(&vmaxw[p * 64 + nt * 16 + l15], __float_as_int(val));
      }
    }
  }
  {
    int p2 = lane >> 3, c0 = (lane & 7) * 8;
    const int* vp = &vmaxw[p2 * 64 + c0];
    float4 r0, r1;
    r0.x = __int_as_float(vp[0]); r0.y = __int_as_float(vp[1]);
    r0.z = __int_as_float(vp[2]); r0.w = __int_as_float(vp[3]);
    r1.x = __int_as_float(vp[4]); r1.y = __int_as_float(vp[5]);
    r1.z = __int_as_float(vp[6]); r1.w = __int_as_float(vp[7]);
    *(float4*)(vert + (size_t)(n0 + p2) * 64 + c0) = r0;
    *(float4*)(vert + (size_t)(n0 + p2) * 64 + c0 + 4) = r1;
  }
}

// ---------------- K7: global max over N per batch ----------------
__global__ void k_gmax(const float* __restrict__ vert, float* __restrict__ g) {
  __shared__ float red[4][64];
  int b = blockIdx.x >> 4, chunk = blockIdx.x & 15;
  int sub = threadIdx.x >> 6, o = threadIdx.x & 63;
  float vm = 0.f;
  for (int j = 0; j < 64; ++j) {
    int r = chunk * 256 + j * 4 + sub;
    vm = fmaxf(vm, vert[(b * NN + r) * 64 + o]);
  }
  red[sub][o] = vm;
  __syncthreads();
  if (sub == 0) {
    float mm = fmaxf(fmaxf(red[0][o], red[1][o]), fmaxf(red[2][o], red[3][o]));
    atomicMax((int*)&g[b * 64 + o], __float_as_int(mm));  // vert >= 0
  }
}

// ---------------- K7b: gb[b] = g[b] @ Wg_bottom + bg ----------------
__global__ void k_gb(const float* __restrict__ g, const float* __restrict__ Wg,
                     const float* __restrict__ bg, float* __restrict__ gb) {
  int t = threadIdx.x;        // 512
  int b = t >> 6, o = t & 63;
  float acc = bg[o];
  #pragma unroll
  for (int i = 0; i < 64; ++i)
    acc = fmaf(g[b * 64 + i], Wg[(64 + i) * 64 + o], acc);
  gb[b * 64 + o] = acc;
}

// ---------------- K8: out = relu(vert @ Wg_top + gb[b]) ----------------
__global__ void k_final(const float* __restrict__ vert, const float* __restrict__ Wg,
                        const float* __restrict__ gb, float* __restrict__ out) {
  __shared__ float Wgs[64 * 64];
  int tid = threadIdx.x, w = tid >> 6, lane = tid & 63;
  for (int i = tid; i < 4096; i += 256) Wgs[i] = Wg[i];
  __syncthreads();
  int gw = blockIdx.x * 4 + w;
  for (int j = 0; j < 4; ++j) {
    int n = gw + 8192 * j;
    int b = n >> 12;
    float vrow = vert[n * 64 + lane];
    float ac0 = gb[b * 64 + lane], ac1 = 0.f, ac2 = 0.f, ac3 = 0.f;
    #pragma unroll
    for (int i = 0; i < 64; i += 4) {
      ac0 = fmaf(__shfl(vrow, i),     Wgs[i * 64 + lane],       ac0);
      ac1 = fmaf(__shfl(vrow, i + 1), Wgs[(i + 1) * 64 + lane], ac1);
      ac2 = fmaf(__shfl(vrow, i + 2), Wgs[(i + 2) * 64 + lane], ac2);
      ac3 = fmaf(__shfl(vrow, i + 3), Wgs[(i + 3) * 64 + lane], ac3);
    }
    out[n * 64 + lane] = fmaxf((ac0 + ac1) + (ac2 + ac3), 0.f);
  }
}

extern "C" void kernel_launch(void* const* d_in, const int* in_sizes, int n_in,
                              void* d_out, int out_size, void* d_ws, size_t ws_size,
                              hipStream_t stream) {
  const float* x     = (const float*)d_in[0];
  const float* gamma = (const float*)d_in[1];
  const float* beta  = (const float*)d_in[2];
  const float* W1    = (const float*)d_in[3];
  const float* b1    = (const float*)d_in[4];
  const float* W2    = (const float*)d_in[5];
  const float* b2    = (const float*)d_in[6];
  const float* W3    = (const float*)d_in[7];
  const float* b3    = (const float*)d_in[8];
  const float* Wg    = (const float*)d_in[9];
  const float* bg    = (const float*)d_in[10];
  float* out = (float*)d_out;

  float* ws    = (float*)d_ws;
  float* stats = ws;                    // 128
  float* ss    = ws + 128;              // 128
  float* xn    = ws + 256;              // 2097152
  float* sq    = xn + 2097152;          // 32768
  int*   knn   = (int*)(sq + 32768);    // 327680 ints
  _Float16* u  = (_Float16*)(knn + 327680);  // 4194304 halfs (2 M floats)
  _Float16* v  = u + 4194304;                // 4194304 halfs
  float* vert  = (float*)(v + 4194304);      // 2097152
  float* g     = vert + 2097152;        // 512
  float* gb    = g + 512;               // 512
  _Float16* xh = (_Float16*)(gb + 512);             // 2097152 halfs (1 M floats)
  _Float16* xl = (_Float16*)(gb + 512 + 1048576);   // 2097152 halfs

  hipMemsetAsync(stats, 0, 128 * sizeof(float), stream);
  hipMemsetAsync(g, 0, 512 * sizeof(float), stream);

  k_bn_stats<<<256, 256, 0, stream>>>(x, stats);
  k_bn_finalize<<<1, 64, 0, stream>>>(stats, gamma, beta, ss);
  k_normalize<<<8192, 256, 0, stream>>>(x, ss, xn, sq, xh, xl);
  k_knn<<<512, 256, 0, stream>>>(xh, xl, sq, knn);
  k_uv<<<512, 256, 0, stream>>>(xn, W1, b1, u, v);
  k_edge<<<1024, 256, 0, stream>>>(u, v, knn, W2, b2, W3, b3, vert);
  k_gmax<<<128, 256, 0, stream>>>(vert, g);
  k_gb<<<1, 512, 0, stream>>>(g, Wg, bg, gb);
  k_final<<<2048, 256, 0, stream>>>(vert, Wg, gb, out);
}

// Round 16
// 446.293 us; speedup vs baseline: 1.1044x; 1.0300x over previous
//
#include <hip/hip_runtime.h>
#include <hip/hip_fp16.h>
#include <float.h>

#define BB 8
#define NN 4096
#define DD 64
#define KNBR 10
#define ROWS (BB*NN)   // 32768

typedef _Float16 f16x8 __attribute__((ext_vector_type(8)));
typedef float f32x4 __attribute__((ext_vector_type(4)));

// ---------------- K1: BN stats (sum, sumsq per feature) ----------------
__global__ void k_bn_stats(const float* __restrict__ x, float* __restrict__ stats) {
  __shared__ float ls[2][4][64];
  int d = threadIdx.x & 63;
  int g = threadIdx.x >> 6;
  float s = 0.f, s2 = 0.f;
  for (int r = blockIdx.x * 4 + g; r < ROWS; r += gridDim.x * 4) {
    float val = x[r * 64 + d];
    s += val;
    s2 = fmaf(val, val, s2);
  }
  ls[0][g][d] = s;
  ls[1][g][d] = s2;
  __syncthreads();
  if (g == 0) {
    atomicAdd(&stats[d],      ls[0][0][d] + ls[0][1][d] + ls[0][2][d] + ls[0][3][d]);
    atomicAdd(&stats[64 + d], ls[1][0][d] + ls[1][1][d] + ls[1][2][d] + ls[1][3][d]);
  }
}

// ---------------- K2: finalize scale/shift ----------------
__global__ void k_bn_finalize(const float* __restrict__ stats,
                              const float* __restrict__ gamma,
                              const float* __restrict__ beta,
                              float* __restrict__ ss) {
  int d = threadIdx.x;  // 64 threads
  const float inv = 1.f / 32768.f;
  float mu  = stats[d] * inv;
  float var = stats[64 + d] * inv - mu * mu;
  float sc  = gamma[d] / sqrtf(var + 1e-5f);
  ss[d]      = sc;
  ss[64 + d] = beta[d] - mu * sc;
}

// ---------------- K3: normalize + row sumsq + f16 hi/lo planes ----------------
__global__ void k_normalize(const float* __restrict__ x, const float* __restrict__ ss,
                            float* __restrict__ xn, float* __restrict__ sq,
                            _Float16* __restrict__ xh, _Float16* __restrict__ xl) {
  int row = blockIdx.x * 4 + (threadIdx.x >> 6);
  int d = threadIdx.x & 63;
  int idx = row * 64 + d;
  float val = fmaf(x[idx], ss[d], ss[64 + d]);
  xn[idx] = val;
  _Float16 h = (_Float16)val;
  _Float16 l = (_Float16)(val - (float)h);
  xh[idx] = h;
  xl[idx] = l;
  float p = val * val;
  #pragma unroll
  for (int off = 32; off > 0; off >>= 1) p += __shfl_xor(p, off);
  if (d == 0) sq[row] = p;
}

// ---------------- K4: KNN, exact two-pass (round-7 kernel, measured 231us) ----------------
__global__ __launch_bounds__(256, 2) void k_knn(const _Float16* __restrict__ xh,
                                                const _Float16* __restrict__ xl,
                                                const float* __restrict__ sq,
                                                int* __restrict__ knn) {
  __shared__ __align__(16) float lds[16640];   // 66560 B = 4 waves x 16640 B
  __shared__ float thrs[64];
  __shared__ int cnts[64];
  const int tid = threadIdx.x;
  const int w = tid >> 6, lane = tid & 63;
  const int l15 = lane & 15, lg = lane >> 4;
  const int b = blockIdx.x >> 6;
  const int rowbase = (blockIdx.x & 63) << 6;
  const int bN = b * NN;
  const _Float16* __restrict__ xhb = xh + (size_t)bN * 64;
  const _Float16* __restrict__ xlb = xl + (size_t)bN * 64;

  char* wbase = (char*)lds + w * 16640;
  char* Bhi = wbase;                    // 32 rows x 64 f16, XOR-swizzled (4096 B)
  char* Blo = wbase + 4096;             // 4096 B
  float* Dw = (float*)(wbase + 8192);   // [64][33] floats (8448 B)

  f16x8 Ah[4][2], Al[4][2];
  #pragma unroll
  for (int mt = 0; mt < 4; ++mt) {
    #pragma unroll
    for (int ks = 0; ks < 2; ++ks) {
      int r = rowbase + mt * 16 + l15;
      Ah[mt][ks] = *(const f16x8*)(xhb + r * 64 + ks * 32 + lg * 8);
      Al[mt][ks] = *(const f16x8*)(xlb + r * 64 + ks * 32 + lg * 8);
    }
  }

  float bd[10];
  #pragma unroll
  for (int i = 0; i < 10; ++i) bd[i] = FLT_MAX;

  int srow[4], scc[4];
  #pragma unroll
  for (int i = 0; i < 4; ++i) { int c = i * 64 + lane; srow[i] = c >> 3; scc[i] = c & 7; }

  f16x8 sh[4], sl[4];
  {
    int mb0 = w * 32;
    #pragma unroll
    for (int i = 0; i < 4; ++i) {
      sh[i] = *(const f16x8*)(xhb + (mb0 + srow[i]) * 64 + scc[i] * 8);
      sl[i] = *(const f16x8*)(xlb + (mb0 + srow[i]) * 64 + scc[i] * 8);
    }
  }

  float* Drow = Dw + lane * 33;

  // ---------------- PASS A: values-only top-10 ----------------
  #pragma unroll 1
  for (int t = 0; t < 32; ++t) {
    const int mb = (t * 4 + w) * 32;
    const int mb2 = (t < 31) ? ((t + 1) * 4 + w) * 32 : mb;
    float sqv0 = sq[bN + mb + l15];
    float sqv1 = sq[bN + mb + 16 + l15];
    #pragma unroll
    for (int i = 0; i < 4; ++i) {
      int off = srow[i] * 128 + 16 * (scc[i] ^ (srow[i] & 7));
      *(f16x8*)(Bhi + off) = sh[i];
      *(f16x8*)(Blo + off) = sl[i];
    }
    #pragma unroll
    for (int i = 0; i < 4; ++i) {
      sh[i] = *(const f16x8*)(xhb + (mb2 + srow[i]) * 64 + scc[i] * 8);
      sl[i] = *(const f16x8*)(xlb + (mb2 + srow[i]) * 64 + scc[i] * 8);
    }
    f16x8 Bh[2][2], Bl[2][2];
    #pragma unroll
    for (int nt = 0; nt < 2; ++nt) {
      #pragma unroll
      for (int ks = 0; ks < 2; ++ks) {
        int rr2 = nt * 16 + l15;
        int off = rr2 * 128 + 16 * ((ks * 4 + lg) ^ (rr2 & 7));
        Bh[nt][ks] = *(const f16x8*)(Bhi + off);
        Bl[nt][ks] = *(const f16x8*)(Blo + off);
      }
    }
    #pragma unroll
    for (int mt = 0; mt < 4; ++mt) {
      f32x4 a0 = {0.f, 0.f, 0.f, 0.f}, a1 = {0.f, 0.f, 0.f, 0.f};
      #pragma unroll
      for (int ks = 0; ks < 2; ++ks) {
        a0 = __builtin_amdgcn_mfma_f32_16x16x32_f16(Ah[mt][ks], Bh[0][ks], a0, 0, 0, 0);
        a1 = __builtin_amdgcn_mfma_f32_16x16x32_f16(Ah[mt][ks], Bh[1][ks], a1, 0, 0, 0);
        a0 = __builtin_amdgcn_mfma_f32_16x16x32_f16(Ah[mt][ks], Bl[0][ks], a0, 0, 0, 0);
        a1 = __builtin_amdgcn_mfma_f32_16x16x32_f16(Ah[mt][ks], Bl[1][ks], a1, 0, 0, 0);
        a0 = __builtin_amdgcn_mfma_f32_16x16x32_f16(Al[mt][ks], Bh[0][ks], a0, 0, 0, 0);
        a1 = __builtin_amdgcn_mfma_f32_16x16x32_f16(Al[mt][ks], Bh[1][ks], a1, 0, 0, 0);
      }
      int rw = mt * 16 + lg * 4;
      #pragma unroll
      for (int r2 = 0; r2 < 4; ++r2) {
        Dw[(rw + r2) * 33 + l15]      = fmaf(-2.f, a0[r2], sqv0);
        Dw[(rw + r2) * 33 + 16 + l15] = fmaf(-2.f, a1[r2], sqv1);
      }
    }
    #pragma unroll 4
    for (int mm = 0; mm < 32; ++mm) {
      float cd = Drow[mm];
      if (cd < bd[9]) {
        float prev = bd[0];
        bd[0] = fminf(cd, bd[0]);
        #pragma unroll
        for (int j = 1; j < 10; ++j) {
          float cur = bd[j];
          bd[j] = fminf(cur, fmaxf(prev, cd));
          prev = cur;
        }
      }
    }
  }

  // ---------------- merge -> per-row exact 10th-smallest threshold ----------------
  __syncthreads();
  float* md = lds;                   // [4][64][10] dists
  #pragma unroll
  for (int i = 0; i < 10; ++i) md[(w * 64 + lane) * 10 + i] = bd[i];
  if (tid < 64) cnts[tid] = 0;
  __syncthreads();
  if (tid < 64) {
    float fd[10];
    #pragma unroll
    for (int i = 0; i < 10; ++i) fd[i] = FLT_MAX;
    for (int w2 = 0; w2 < 4; ++w2) {
      #pragma unroll
      for (int kk = 0; kk < 10; ++kk) {
        float cd = md[(w2 * 64 + tid) * 10 + kk];
        if (cd < fd[9]) {
          float prev = fd[0];
          fd[0] = fminf(cd, fd[0]);
          #pragma unroll
          for (int j = 1; j < 10; ++j) {
            float cur = fd[j];
            fd[j] = fminf(cur, fmaxf(prev, cd));
            prev = cur;
          }
        }
      }
    }
    thrs[tid] = fd[9];
  }
  __syncthreads();

  float thv[4][4];
  #pragma unroll
  for (int mt = 0; mt < 4; ++mt)
    #pragma unroll
    for (int r2 = 0; r2 < 4; ++r2)
      thv[mt][r2] = thrs[mt * 16 + lg * 4 + r2];

  int* knnrow = knn + (size_t)(bN + rowbase) * KNBR;

  // ---------------- PASS B: recompute + threshold-append ----------------
  {
    int mb0 = w * 32;
    #pragma unroll
    for (int i = 0; i < 4; ++i) {
      sh[i] = *(const f16x8*)(xhb + (mb0 + srow[i]) * 64 + scc[i] * 8);
      sl[i] = *(const f16x8*)(xlb + (mb0 + srow[i]) * 64 + scc[i] * 8);
    }
  }
  #pragma unroll 1
  for (int t = 0; t < 32; ++t) {
    const int mb = (t * 4 + w) * 32;
    const int mb2 = (t < 31) ? ((t + 1) * 4 + w) * 32 : mb;
    float sqv0 = sq[bN + mb + l15];
    float sqv1 = sq[bN + mb + 16 + l15];
    #pragma unroll
    for (int i = 0; i < 4; ++i) {
      int off = srow[i] * 128 + 16 * (scc[i] ^ (srow[i] & 7));
      *(f16x8*)(Bhi + off) = sh[i];
      *(f16x8*)(Blo + off) = sl[i];
    }
    #pragma unroll
    for (int i = 0; i < 4; ++i) {
      sh[i] = *(const f16x8*)(xhb + (mb2 + srow[i]) * 64 + scc[i] * 8);
      sl[i] = *(const f16x8*)(xlb + (mb2 + srow[i]) * 64 + scc[i] * 8);
    }
    f16x8 Bh[2][2], Bl[2][2];
    #pragma unroll
    for (int nt = 0; nt < 2; ++nt) {
      #pragma unroll
      for (int ks = 0; ks < 2; ++ks) {
        int rr2 = nt * 16 + l15;
        int off = rr2 * 128 + 16 * ((ks * 4 + lg) ^ (rr2 & 7));
        Bh[nt][ks] = *(const f16x8*)(Bhi + off);
        Bl[nt][ks] = *(const f16x8*)(Blo + off);
      }
    }
    #pragma unroll
    for (int mt = 0; mt < 4; ++mt) {
      f32x4 a0 = {0.f, 0.f, 0.f, 0.f}, a1 = {0.f, 0.f, 0.f, 0.f};
      #pragma unroll
      for (int ks = 0; ks < 2; ++ks) {
        a0 = __builtin_amdgcn_mfma_f32_16x16x32_f16(Ah[mt][ks], Bh[0][ks], a0, 0, 0, 0);
        a1 = __builtin_amdgcn_mfma_f32_16x16x32_f16(Ah[mt][ks], Bh[1][ks], a1, 0, 0, 0);
        a0 = __builtin_amdgcn_mfma_f32_16x16x32_f16(Ah[mt][ks], Bl[0][ks], a0, 0, 0, 0);
        a1 = __builtin_amdgcn_mfma_f32_16x16x32_f16(Ah[mt][ks], Bl[1][ks], a1, 0, 0, 0);
        a0 = __builtin_amdgcn_mfma_f32_16x16x32_f16(Al[mt][ks], Bh[0][ks], a0, 0, 0, 0);
        a1 = __builtin_amdgcn_mfma_f32_16x16x32_f16(Al[mt][ks], Bh[1][ks], a1, 0, 0, 0);
      }
      #pragma unroll
      for (int r2 = 0; r2 < 4; ++r2) {
        float d0 = fmaf(-2.f, a0[r2], sqv0);
        float d1 = fmaf(-2.f, a1[r2], sqv1);
        int row = mt * 16 + lg * 4 + r2;
        if (d0 <= thv[mt][r2]) {
          int slot = atomicAdd(&cnts[row], 1);
          if (slot < KNBR) knnrow[row * KNBR + slot] = bN + mb + l15;
        }
        if (d1 <= thv[mt][r2]) {
          int slot = atomicAdd(&cnts[row], 1);
          if (slot < KNBR) knnrow[row * KNBR + slot] = bN + mb + 16 + l15;
        }
      }
    }
  }
}

// ---------------- K5: U/V precompute -> f16 output ----------------
__global__ void k_uv(const float* __restrict__ xn, const float* __restrict__ W1,
                     const float* __restrict__ b1, _Float16* __restrict__ u,
                     _Float16* __restrict__ v) {
  __shared__ float xs[64 * 64];   // 16 KB
  const int tid = threadIdx.x;
  const int o = tid & 127;
  const bool isU = tid < 128;
  const int rowbase = blockIdx.x * 64;

  float wreg[64];
  #pragma unroll
  for (int d = 0; d < 64; ++d) {
    float bw = W1[(64 + d) * 128 + o];
    wreg[d] = isU ? (W1[d * 128 + o] + bw) : bw;
  }
  const float bb = isU ? b1[o] : 0.f;
  _Float16* __restrict__ dst = isU ? u : v;

  {
    const float4* s4 = (const float4*)(xn + rowbase * 64);
    float4* d4 = (float4*)xs;
    #pragma unroll
    for (int i = 0; i < 4; ++i) d4[tid + 256 * i] = s4[tid + 256 * i];
  }
  __syncthreads();

  for (int r = 0; r < 64; ++r) {
    const float4* xr = (const float4*)(xs + r * 64);
    float a0 = bb, a1 = 0.f, a2 = 0.f, a3 = 0.f;
    #pragma unroll
    for (int q = 0; q < 16; ++q) {
      float4 xv = xr[q];
      a0 = fmaf(xv.x, wreg[4 * q + 0], a0);
      a1 = fmaf(xv.y, wreg[4 * q + 1], a1);
      a2 = fmaf(xv.z, wreg[4 * q + 2], a2);
      a3 = fmaf(xv.w, wreg[4 * q + 3], a3);
    }
    dst[(rowbase + r) * 128 + o] = (_Float16)((a0 + a1) + (a2 + a3));
  }
}

// ---------------- K6: edge MLP + fused per-batch global max ----------------
// Block covers 32 consecutive points (single batch). After per-wave vert
// write-out, block-level LDS max then one global atomicMax per feature.
__global__ __launch_bounds__(256, 2) void k_edge(const _Float16* __restrict__ uu,
                                                 const _Float16* __restrict__ vv,
                                                 const int* __restrict__ knn,
                                                 const float* __restrict__ W2,
                                                 const float* __restrict__ b2,
                                                 const float* __restrict__ W3,
                                                 const float* __restrict__ b3,
                                                 float* __restrict__ vert,
                                                 float* __restrict__ gmax) {
  __shared__ __align__(16) _Float16 W3Ts[64 * 72];        // W3T[out][k2], 9216 B
  __shared__ __align__(16) _Float16 h2buf[4][16 * 88];    // per-wave, 2816 B each
  __shared__ int vmaxs[4][512];                           // per-wave [8 pts][64]
  __shared__ int gblk[64];                                // block max per feature
  const int tid = threadIdx.x;
  const int w = tid >> 6, lane = tid & 63;
  const int l15 = lane & 15, lg = lane >> 4;

  for (int i = tid; i < 64 * 64; i += 256) {
    int o3 = i >> 6, k2 = i & 63;
    W3Ts[o3 * 72 + k2] = (_Float16)W3[k2 * 64 + o3];
  }
  f16x8 w2f[4][4];
  #pragma unroll
  for (int ks = 0; ks < 4; ++ks) {
    #pragma unroll
    for (int nt = 0; nt < 4; ++nt) {
      f16x8 t;
      #pragma unroll
      for (int j = 0; j < 8; ++j)
        t[j] = (_Float16)W2[(ks * 32 + lg * 8 + j) * 64 + nt * 16 + l15];
      w2f[ks][nt] = t;
    }
  }
  float bias2[4], bias3[4];
  #pragma unroll
  for (int nt = 0; nt < 4; ++nt) { bias2[nt] = b2[nt * 16 + l15]; bias3[nt] = b3[nt * 16 + l15]; }

  _Float16* h2w = h2buf[w];
  int* vmaxw = vmaxs[w];
  #pragma unroll
  for (int q = 0; q < 8; ++q) vmaxw[lane * 8 + q] = 0;
  if (tid < 64) gblk[tid] = 0;
  __syncthreads();   // W3Ts + gblk ready

  const int g = blockIdx.x * 4 + w;   // 4096 groups
  const int n0 = g * 8;
  const int ebase = n0 * KNBR;
  #pragma unroll 1
  for (int mt = 0; mt < 5; ++mt) {
    const int e = mt * 16 + l15;
    const int m = knn[ebase + e];
    const int n = n0 + e / 10;
    const _Float16* Up = uu + (size_t)n * 128 + lg * 8;
    const _Float16* Vp = vv + (size_t)m * 128 + lg * 8;
    f16x8 A[4];
    #pragma unroll
    for (int ks = 0; ks < 4; ++ks) {
      f16x8 ud = *(const f16x8*)(Up + ks * 32);
      f16x8 vd = *(const f16x8*)(Vp + ks * 32);
      f16x8 df = ud - vd;                 // v_pk_sub_f16
      f16x8 t;
      #pragma unroll
      for (int j = 0; j < 8; ++j)
        t[j] = df[j] > (_Float16)0.f ? df[j] : (_Float16)0.f;  // v_pk_max_f16
      A[ks] = t;
    }
    f32x4 acc[4];
    #pragma unroll
    for (int nt = 0; nt < 4; ++nt) { float bbv = bias2[nt]; acc[nt] = (f32x4){bbv, bbv, bbv, bbv}; }
    #pragma unroll
    for (int ks = 0; ks < 4; ++ks) {
      #pragma unroll
      for (int nt = 0; nt < 4; ++nt)
        acc[nt] = __builtin_amdgcn_mfma_f32_16x16x32_f16(A[ks], w2f[ks][nt], acc[nt], 0, 0, 0);
    }
    #pragma unroll
    for (int nt = 0; nt < 4; ++nt) {
      #pragma unroll
      for (int r = 0; r < 4; ++r)
        h2w[(lg * 4 + r) * 88 + nt * 16 + l15] = (_Float16)fmaxf(acc[nt][r], 0.f);
    }
    f16x8 A3[2];
    #pragma unroll
    for (int ks2 = 0; ks2 < 2; ++ks2)
      A3[ks2] = *(const f16x8*)(h2w + l15 * 88 + ks2 * 32 + lg * 8);
    f32x4 c3[4];
    #pragma unroll
    for (int nt = 0; nt < 4; ++nt) { float bbv = bias3[nt]; c3[nt] = (f32x4){bbv, bbv, bbv, bbv}; }
    #pragma unroll
    for (int ks2 = 0; ks2 < 2; ++ks2) {
      #pragma unroll
      for (int nt = 0; nt < 4; ++nt) {
        f16x8 bf = *(const f16x8*)(W3Ts + (nt * 16 + l15) * 72 + ks2 * 32 + lg * 8);
        c3[nt] = __builtin_amdgcn_mfma_f32_16x16x32_f16(A3[ks2], bf, c3[nt], 0, 0, 0);
      }
    }
    #pragma unroll
    for (int nt = 0; nt < 4; ++nt) {
      #pragma unroll
      for (int r = 0; r < 4; ++r) {
        float val = fmaxf(c3[nt][r], 0.f);
        int e2 = mt * 16 + lg * 4 + r;
        int p = e2 / 10;
        atomicMax(&vmaxw[p * 64 + nt * 16 + l15], __float_as_int(val));
      }
    }
  }
  {
    int p2 = lane >> 3, c0 = (lane & 7) * 8;
    const int* vp = &vmaxw[p2 * 64 + c0];
    float4 r0, r1;
    r0.x = __int_as_float(vp[0]); r0.y = __int_as_float(vp[1]);
    r0.z = __int_as_float(vp[2]); r0.w = __int_as_float(vp[3]);
    r1.x = __int_as_float(vp[4]); r1.y = __int_as_float(vp[5]);
    r1.z = __int_as_float(vp[6]); r1.w = __int_as_float(vp[7]);
    *(float4*)(vert + (size_t)(n0 + p2) * 64 + c0) = r0;
    *(float4*)(vert + (size_t)(n0 + p2) * 64 + c0 + 4) = r1;
    // block-level max for fused k_gmax (values >= 0)
    atomicMax(&gblk[c0 + 0], __float_as_int(r0.x));
    atomicMax(&gblk[c0 + 1], __float_as_int(r0.y));
    atomicMax(&gblk[c0 + 2], __float_as_int(r0.z));
    atomicMax(&gblk[c0 + 3], __float_as_int(r0.w));
    atomicMax(&gblk[c0 + 4], __float_as_int(r1.x));
    atomicMax(&gblk[c0 + 5], __float_as_int(r1.y));
    atomicMax(&gblk[c0 + 6], __float_as_int(r1.z));
    atomicMax(&gblk[c0 + 7], __float_as_int(r1.w));
  }
  __syncthreads();
  if (tid < 64) {
    int bb2 = (blockIdx.x * 32) >> 12;   // block's batch (32 pts, single batch)
    atomicMax((int*)&gmax[bb2 * 64 + tid], gblk[tid]);
  }
}

// ---------------- K8: out = relu(vert @ Wg_top + gb[b]); gb computed in-block ----------------
__global__ void k_final(const float* __restrict__ vert, const float* __restrict__ Wg,
                        const float* __restrict__ bg, const float* __restrict__ gmax,
                        float* __restrict__ out) {
  __shared__ float Wgs[64 * 64];
  __shared__ float gbs[8 * 64];
  int tid = threadIdx.x, w = tid >> 6, lane = tid & 63;
  for (int i = tid; i < 4096; i += 256) Wgs[i] = Wg[i];  // rows 0..63
  for (int t2 = tid; t2 < 512; t2 += 256) {              // fused k_gb
    int b_ = t2 >> 6, o = t2 & 63;
    float acc = bg[o];
    #pragma unroll
    for (int i = 0; i < 64; ++i)
      acc = fmaf(gmax[b_ * 64 + i], Wg[(64 + i) * 64 + o], acc);
    gbs[t2] = acc;
  }
  __syncthreads();
  int gw = blockIdx.x * 4 + w;
  for (int j = 0; j < 4; ++j) {
    int n = gw + 8192 * j;
    int b = n >> 12;
    float vrow = vert[n * 64 + lane];
    float ac0 = gbs[b * 64 + lane], ac1 = 0.f, ac2 = 0.f, ac3 = 0.f;
    #pragma unroll
    for (int i = 0; i < 64; i += 4) {
      ac0 = fmaf(__shfl(vrow, i),     Wgs[i * 64 + lane],       ac0);
      ac1 = fmaf(__shfl(vrow, i + 1), Wgs[(i + 1) * 64 + lane], ac1);
      ac2 = fmaf(__shfl(vrow, i + 2), Wgs[(i + 2) * 64 + lane], ac2);
      ac3 = fmaf(__shfl(vrow, i + 3), Wgs[(i + 3) * 64 + lane], ac3);
    }
    out[n * 64 + lane] = fmaxf((ac0 + ac1) + (ac2 + ac3), 0.f);
  }
}

extern "C" void kernel_launch(void* const* d_in, const int* in_sizes, int n_in,
                              void* d_out, int out_size, void* d_ws, size_t ws_size,
                              hipStream_t stream) {
  const float* x     = (const float*)d_in[0];
  const float* gamma = (const float*)d_in[1];
  const float* beta  = (const float*)d_in[2];
  const float* W1    = (const float*)d_in[3];
  const float* b1    = (const float*)d_in[4];
  const float* W2    = (const float*)d_in[5];
  const float* b2    = (const float*)d_in[6];
  const float* W3    = (const float*)d_in[7];
  const float* b3    = (const float*)d_in[8];
  const float* Wg    = (const float*)d_in[9];
  const float* bg    = (const float*)d_in[10];
  float* out = (float*)d_out;

  float* ws    = (float*)d_ws;
  float* stats = ws;                    // 128
  float* ss    = ws + 128;              // 128
  float* xn    = ws + 256;              // 2097152
  float* sq    = xn + 2097152;          // 32768
  int*   knn   = (int*)(sq + 32768);    // 327680 ints
  _Float16* u  = (_Float16*)(knn + 327680);  // 4194304 halfs
  _Float16* v  = u + 4194304;                // 4194304 halfs
  float* vert  = (float*)(v + 4194304);      // 2097152
  float* g     = vert + 2097152;        // 512
  _Float16* xh = (_Float16*)(g + 512);              // 2097152 halfs
  _Float16* xl = (_Float16*)(g + 512 + 1048576);    // 2097152 halfs

  hipMemsetAsync(stats, 0, 128 * sizeof(float), stream);
  hipMemsetAsync(g, 0, 512 * sizeof(float), stream);

  k_bn_stats<<<256, 256, 0, stream>>>(x, stats);
  k_bn_finalize<<<1, 64, 0, stream>>>(stats, gamma, beta, ss);
  k_normalize<<<8192, 256, 0, stream>>>(x, ss, xn, sq, xh, xl);
  k_knn<<<512, 256, 0, stream>>>(xh, xl, sq, knn);
  k_uv<<<512, 256, 0, stream>>>(xn, W1, b1, u, v);
  k_edge<<<1024, 256, 0, stream>>>(u, v, knn, W2, b2, W3, b3, vert, g);
  k_final<<<2048, 256, 0, stream>>>(vert, Wg, bg, g, out);
}

// Round 17
// 444.228 us; speedup vs baseline: 1.1096x; 1.0046x over previous
//
#include <hip/hip_runtime.h>
#include <hip/hip_fp16.h>
#include <float.h>

#define BB 8
#define NN 4096
#define DD 64
#define KNBR 10
#define ROWS (BB*NN)   // 32768

typedef _Float16 f16x8 __attribute__((ext_vector_type(8)));
typedef float f32x4 __attribute__((ext_vector_type(4)));

// ---------------- K1: BN stats (sum, sumsq per feature) ----------------
__global__ void k_bn_stats(const float* __restrict__ x, float* __restrict__ stats) {
  __shared__ float ls[2][4][64];
  int d = threadIdx.x & 63;
  int g = threadIdx.x >> 6;
  float s = 0.f, s2 = 0.f;
  for (int r = blockIdx.x * 4 + g; r < ROWS; r += gridDim.x * 4) {
    float val = x[r * 64 + d];
    s += val;
    s2 = fmaf(val, val, s2);
  }
  ls[0][g][d] = s;
  ls[1][g][d] = s2;
  __syncthreads();
  if (g == 0) {
    atomicAdd(&stats[d],      ls[0][0][d] + ls[0][1][d] + ls[0][2][d] + ls[0][3][d]);
    atomicAdd(&stats[64 + d], ls[1][0][d] + ls[1][1][d] + ls[1][2][d] + ls[1][3][d]);
  }
}

// ---------------- K2: finalize scale/shift ----------------
__global__ void k_bn_finalize(const float* __restrict__ stats,
                              const float* __restrict__ gamma,
                              const float* __restrict__ beta,
                              float* __restrict__ ss) {
  int d = threadIdx.x;  // 64 threads
  const float inv = 1.f / 32768.f;
  float mu  = stats[d] * inv;
  float var = stats[64 + d] * inv - mu * mu;
  float sc  = gamma[d] / sqrtf(var + 1e-5f);
  ss[d]      = sc;
  ss[64 + d] = beta[d] - mu * sc;
}

// ---------------- K3: normalize + row sumsq + f16 hi/lo planes ----------------
__global__ void k_normalize(const float* __restrict__ x, const float* __restrict__ ss,
                            float* __restrict__ xn, float* __restrict__ sq,
                            _Float16* __restrict__ xh, _Float16* __restrict__ xl) {
  int row = blockIdx.x * 4 + (threadIdx.x >> 6);
  int d = threadIdx.x & 63;
  int idx = row * 64 + d;
  float val = fmaf(x[idx], ss[d], ss[64 + d]);
  xn[idx] = val;
  _Float16 h = (_Float16)val;
  _Float16 l = (_Float16)(val - (float)h);
  xh[idx] = h;
  xl[idx] = l;
  float p = val * val;
  #pragma unroll
  for (int off = 32; off > 0; off >>= 1) p += __shfl_xor(p, off);
  if (d == 0) sq[row] = p;
}

// ---------------- K4: KNN, exact two-pass; pass-A scan = 4 independent ----------------
// branchless med3 chains per lane (mm%4 -> chain; partition => union of
// per-chain top-10s contains the true top-10; merged once at end). Breaks
// the 10-deep dependent med3 chain into 4-way ILP (latency-bound at 2
// waves/SIMD). Rest identical to the round-7 structure (231us measured).
__global__ __launch_bounds__(256, 2) void k_knn(const _Float16* __restrict__ xh,
                                                const _Float16* __restrict__ xl,
                                                const float* __restrict__ sq,
                                                int* __restrict__ knn) {
  __shared__ __align__(16) float lds[16640];   // 66560 B = 4 waves x 16640 B
  __shared__ float thrs[64];
  __shared__ int cnts[64];
  const int tid = threadIdx.x;
  const int w = tid >> 6, lane = tid & 63;
  const int l15 = lane & 15, lg = lane >> 4;
  const int b = blockIdx.x >> 6;
  const int rowbase = (blockIdx.x & 63) << 6;
  const int bN = b * NN;
  const _Float16* __restrict__ xhb = xh + (size_t)bN * 64;
  const _Float16* __restrict__ xlb = xl + (size_t)bN * 64;

  char* wbase = (char*)lds + w * 16640;
  char* Bhi = wbase;                    // 32 rows x 64 f16, XOR-swizzled (4096 B)
  char* Blo = wbase + 4096;             // 4096 B
  float* Dw = (float*)(wbase + 8192);   // [64][33] floats (8448 B)

  f16x8 Ah[4][2], Al[4][2];
  #pragma unroll
  for (int mt = 0; mt < 4; ++mt) {
    #pragma unroll
    for (int ks = 0; ks < 2; ++ks) {
      int r = rowbase + mt * 16 + l15;
      Ah[mt][ks] = *(const f16x8*)(xhb + r * 64 + ks * 32 + lg * 8);
      Al[mt][ks] = *(const f16x8*)(xlb + r * 64 + ks * 32 + lg * 8);
    }
  }

  float bd[4][10];   // 4 independent chains
  #pragma unroll
  for (int c = 0; c < 4; ++c)
    #pragma unroll
    for (int i = 0; i < 10; ++i) bd[c][i] = FLT_MAX;

  int srow[4], scc[4];
  #pragma unroll
  for (int i = 0; i < 4; ++i) { int c = i * 64 + lane; srow[i] = c >> 3; scc[i] = c & 7; }

  f16x8 sh[4], sl[4];
  {
    int mb0 = w * 32;
    #pragma unroll
    for (int i = 0; i < 4; ++i) {
      sh[i] = *(const f16x8*)(xhb + (mb0 + srow[i]) * 64 + scc[i] * 8);
      sl[i] = *(const f16x8*)(xlb + (mb0 + srow[i]) * 64 + scc[i] * 8);
    }
  }

  float* Drow = Dw + lane * 33;

  // ---------------- PASS A: values-only top-10, 4-chain ILP scan ----------------
  #pragma unroll 1
  for (int t = 0; t < 32; ++t) {
    const int mb = (t * 4 + w) * 32;
    const int mb2 = (t < 31) ? ((t + 1) * 4 + w) * 32 : mb;
    float sqv0 = sq[bN + mb + l15];
    float sqv1 = sq[bN + mb + 16 + l15];
    #pragma unroll
    for (int i = 0; i < 4; ++i) {
      int off = srow[i] * 128 + 16 * (scc[i] ^ (srow[i] & 7));
      *(f16x8*)(Bhi + off) = sh[i];
      *(f16x8*)(Blo + off) = sl[i];
    }
    #pragma unroll
    for (int i = 0; i < 4; ++i) {
      sh[i] = *(const f16x8*)(xhb + (mb2 + srow[i]) * 64 + scc[i] * 8);
      sl[i] = *(const f16x8*)(xlb + (mb2 + srow[i]) * 64 + scc[i] * 8);
    }
    f16x8 Bh[2][2], Bl[2][2];
    #pragma unroll
    for (int nt = 0; nt < 2; ++nt) {
      #pragma unroll
      for (int ks = 0; ks < 2; ++ks) {
        int rr2 = nt * 16 + l15;
        int off = rr2 * 128 + 16 * ((ks * 4 + lg) ^ (rr2 & 7));
        Bh[nt][ks] = *(const f16x8*)(Bhi + off);
        Bl[nt][ks] = *(const f16x8*)(Blo + off);
      }
    }
    #pragma unroll
    for (int mt = 0; mt < 4; ++mt) {
      f32x4 a0 = {0.f, 0.f, 0.f, 0.f}, a1 = {0.f, 0.f, 0.f, 0.f};
      #pragma unroll
      for (int ks = 0; ks < 2; ++ks) {
        a0 = __builtin_amdgcn_mfma_f32_16x16x32_f16(Ah[mt][ks], Bh[0][ks], a0, 0, 0, 0);
        a1 = __builtin_amdgcn_mfma_f32_16x16x32_f16(Ah[mt][ks], Bh[1][ks], a1, 0, 0, 0);
        a0 = __builtin_amdgcn_mfma_f32_16x16x32_f16(Ah[mt][ks], Bl[0][ks], a0, 0, 0, 0);
        a1 = __builtin_amdgcn_mfma_f32_16x16x32_f16(Ah[mt][ks], Bl[1][ks], a1, 0, 0, 0);
        a0 = __builtin_amdgcn_mfma_f32_16x16x32_f16(Al[mt][ks], Bh[0][ks], a0, 0, 0, 0);
        a1 = __builtin_amdgcn_mfma_f32_16x16x32_f16(Al[mt][ks], Bh[1][ks], a1, 0, 0, 0);
      }
      int rw = mt * 16 + lg * 4;
      #pragma unroll
      for (int r2 = 0; r2 < 4; ++r2) {
        Dw[(rw + r2) * 33 + l15]      = fmaf(-2.f, a0[r2], sqv0);
        Dw[(rw + r2) * 33 + 16 + l15] = fmaf(-2.f, a1[r2], sqv1);
      }
    }
    // branchless 4-chain scan: mm%4 -> chain c, independent med3 chains
    #pragma unroll
    for (int mm = 0; mm < 32; mm += 4) {
      #pragma unroll
      for (int c = 0; c < 4; ++c) {
        float cd = Drow[mm + c];
        float prev = bd[c][0];
        bd[c][0] = fminf(cd, prev);
        #pragma unroll
        for (int j = 1; j < 10; ++j) {
          float cur = bd[c][j];
          bd[c][j] = fminf(cur, fmaxf(prev, cd));   // -> v_med3_f32
          prev = cur;
        }
      }
    }
  }

  // merge chains 1..3 into chain 0 (branchy, runs once)
  #pragma unroll
  for (int c = 1; c < 4; ++c) {
    #pragma unroll 1
    for (int i = 0; i < 10; ++i) {
      float cd = bd[c][i];
      if (cd < bd[0][9]) {
        float prev = bd[0][0];
        bd[0][0] = fminf(cd, prev);
        #pragma unroll
        for (int j = 1; j < 10; ++j) {
          float cur = bd[0][j];
          bd[0][j] = fminf(cur, fmaxf(prev, cd));
          prev = cur;
        }
      } else break;   // chain lists sorted ascending
    }
  }

  // ---------------- merge -> per-row exact 10th-smallest threshold ----------------
  __syncthreads();
  float* md = lds;                   // [4][64][10] dists
  #pragma unroll
  for (int i = 0; i < 10; ++i) md[(w * 64 + lane) * 10 + i] = bd[0][i];
  if (tid < 64) cnts[tid] = 0;
  __syncthreads();
  if (tid < 64) {
    float fd[10];
    #pragma unroll
    for (int i = 0; i < 10; ++i) fd[i] = FLT_MAX;
    for (int w2 = 0; w2 < 4; ++w2) {
      #pragma unroll
      for (int kk = 0; kk < 10; ++kk) {
        float cd = md[(w2 * 64 + tid) * 10 + kk];
        if (cd < fd[9]) {
          float prev = fd[0];
          fd[0] = fminf(cd, fd[0]);
          #pragma unroll
          for (int j = 1; j < 10; ++j) {
            float cur = fd[j];
            fd[j] = fminf(cur, fmaxf(prev, cd));
            prev = cur;
          }
        }
      }
    }
    thrs[tid] = fd[9];
  }
  __syncthreads();

  float thv[4][4];
  #pragma unroll
  for (int mt = 0; mt < 4; ++mt)
    #pragma unroll
    for (int r2 = 0; r2 < 4; ++r2)
      thv[mt][r2] = thrs[mt * 16 + lg * 4 + r2];

  int* knnrow = knn + (size_t)(bN + rowbase) * KNBR;

  // ---------------- PASS B: recompute + threshold-append ----------------
  {
    int mb0 = w * 32;
    #pragma unroll
    for (int i = 0; i < 4; ++i) {
      sh[i] = *(const f16x8*)(xhb + (mb0 + srow[i]) * 64 + scc[i] * 8);
      sl[i] = *(const f16x8*)(xlb + (mb0 + srow[i]) * 64 + scc[i] * 8);
    }
  }
  #pragma unroll 1
  for (int t = 0; t < 32; ++t) {
    const int mb = (t * 4 + w) * 32;
    const int mb2 = (t < 31) ? ((t + 1) * 4 + w) * 32 : mb;
    float sqv0 = sq[bN + mb + l15];
    float sqv1 = sq[bN + mb + 16 + l15];
    #pragma unroll
    for (int i = 0; i < 4; ++i) {
      int off = srow[i] * 128 + 16 * (scc[i] ^ (srow[i] & 7));
      *(f16x8*)(Bhi + off) = sh[i];
      *(f16x8*)(Blo + off) = sl[i];
    }
    #pragma unroll
    for (int i = 0; i < 4; ++i) {
      sh[i] = *(const f16x8*)(xhb + (mb2 + srow[i]) * 64 + scc[i] * 8);
      sl[i] = *(const f16x8*)(xlb + (mb2 + srow[i]) * 64 + scc[i] * 8);
    }
    f16x8 Bh[2][2], Bl[2][2];
    #pragma unroll
    for (int nt = 0; nt < 2; ++nt) {
      #pragma unroll
      for (int ks = 0; ks < 2; ++ks) {
        int rr2 = nt * 16 + l15;
        int off = rr2 * 128 + 16 * ((ks * 4 + lg) ^ (rr2 & 7));
        Bh[nt][ks] = *(const f16x8*)(Bhi + off);
        Bl[nt][ks] = *(const f16x8*)(Blo + off);
      }
    }
    #pragma unroll
    for (int mt = 0; mt < 4; ++mt) {
      f32x4 a0 = {0.f, 0.f, 0.f, 0.f}, a1 = {0.f, 0.f, 0.f, 0.f};
      #pragma unroll
      for (int ks = 0; ks < 2; ++ks) {
        a0 = __builtin_amdgcn_mfma_f32_16x16x32_f16(Ah[mt][ks], Bh[0][ks], a0, 0, 0, 0);
        a1 = __builtin_amdgcn_mfma_f32_16x16x32_f16(Ah[mt][ks], Bh[1][ks], a1, 0, 0, 0);
        a0 = __builtin_amdgcn_mfma_f32_16x16x32_f16(Ah[mt][ks], Bl[0][ks], a0, 0, 0, 0);
        a1 = __builtin_amdgcn_mfma_f32_16x16x32_f16(Ah[mt][ks], Bl[1][ks], a1, 0, 0, 0);
        a0 = __builtin_amdgcn_mfma_f32_16x16x32_f16(Al[mt][ks], Bh[0][ks], a0, 0, 0, 0);
        a1 = __builtin_amdgcn_mfma_f32_16x16x32_f16(Al[mt][ks], Bh[1][ks], a1, 0, 0, 0);
      }
      #pragma unroll
      for (int r2 = 0; r2 < 4; ++r2) {
        float d0 = fmaf(-2.f, a0[r2], sqv0);
        float d1 = fmaf(-2.f, a1[r2], sqv1);
        int row = mt * 16 + lg * 4 + r2;
        if (d0 <= thv[mt][r2]) {
          int slot = atomicAdd(&cnts[row], 1);
          if (slot < KNBR) knnrow[row * KNBR + slot] = bN + mb + l15;
        }
        if (d1 <= thv[mt][r2]) {
          int slot = atomicAdd(&cnts[row], 1);
          if (slot < KNBR) knnrow[row * KNBR + slot] = bN + mb + 16 + l15;
        }
      }
    }
  }
}

// ---------------- K5: U/V precompute -> f16 output ----------------
__global__ void k_uv(const float* __restrict__ xn, const float* __restrict__ W1,
                     const float* __restrict__ b1, _Float16* __restrict__ u,
                     _Float16* __restrict__ v) {
  __shared__ float xs[64 * 64];   // 16 KB
  const int tid = threadIdx.x;
  const int o = tid & 127;
  const bool isU = tid < 128;
  const int rowbase = blockIdx.x * 64;

  float wreg[64];
  #pragma unroll
  for (int d = 0; d < 64; ++d) {
    float bw = W1[(64 + d) * 128 + o];
    wreg[d] = isU ? (W1[d * 128 + o] + bw) : bw;
  }
  const float bb = isU ? b1[o] : 0.f;
  _Float16* __restrict__ dst = isU ? u : v;

  {
    const float4* s4 = (const float4*)(xn + rowbase * 64);
    float4* d4 = (float4*)xs;
    #pragma unroll
    for (int i = 0; i < 4; ++i) d4[tid + 256 * i] = s4[tid + 256 * i];
  }
  __syncthreads();

  for (int r = 0; r < 64; ++r) {
    const float4* xr = (const float4*)(xs + r * 64);
    float a0 = bb, a1 = 0.f, a2 = 0.f, a3 = 0.f;
    #pragma unroll
    for (int q = 0; q < 16; ++q) {
      float4 xv = xr[q];
      a0 = fmaf(xv.x, wreg[4 * q + 0], a0);
      a1 = fmaf(xv.y, wreg[4 * q + 1], a1);
      a2 = fmaf(xv.z, wreg[4 * q + 2], a2);
      a3 = fmaf(xv.w, wreg[4 * q + 3], a3);
    }
    dst[(rowbase + r) * 128 + o] = (_Float16)((a0 + a1) + (a2 + a3));
  }
}

// ---------------- K6: edge MLP + fused per-batch global max ----------------
__global__ __launch_bounds__(256, 2) void k_edge(const _Float16* __restrict__ uu,
                                                 const _Float16* __restrict__ vv,
                                                 const int* __restrict__ knn,
                                                 const float* __restrict__ W2,
                                                 const float* __restrict__ b2,
                                                 const float* __restrict__ W3,
                                                 const float* __restrict__ b3,
                                                 float* __restrict__ vert,
                                                 float* __restrict__ gmax) {
  __shared__ __align__(16) _Float16 W3Ts[64 * 72];        // W3T[out][k2], 9216 B
  __shared__ __align__(16) _Float16 h2buf[4][16 * 88];    // per-wave, 2816 B each
  __shared__ int vmaxs[4][512];                           // per-wave [8 pts][64]
  __shared__ int gblk[64];                                // block max per feature
  const int tid = threadIdx.x;
  const int w = tid >> 6, lane = tid & 63;
  const int l15 = lane & 15, lg = lane >> 4;

  for (int i = tid; i < 64 * 64; i += 256) {
    int o3 = i >> 6, k2 = i & 63;
    W3Ts[o3 * 72 + k2] = (_Float16)W3[k2 * 64 + o3];
  }
  f16x8 w2f[4][4];
  #pragma unroll
  for (int ks = 0; ks < 4; ++ks) {
    #pragma unroll
    for (int nt = 0; nt < 4; ++nt) {
      f16x8 t;
      #pragma unroll
      for (int j = 0; j < 8; ++j)
        t[j] = (_Float16)W2[(ks * 32 + lg * 8 + j) * 64 + nt * 16 + l15];
      w2f[ks][nt] = t;
    }
  }
  float bias2[4], bias3[4];
  #pragma unroll
  for (int nt = 0; nt < 4; ++nt) { bias2[nt] = b2[nt * 16 + l15]; bias3[nt] = b3[nt * 16 + l15]; }

  _Float16* h2w = h2buf[w];
  int* vmaxw = vmaxs[w];
  #pragma unroll
  for (int q = 0; q < 8; ++q) vmaxw[lane * 8 + q] = 0;
  if (tid < 64) gblk[tid] = 0;
  __syncthreads();   // W3Ts + gblk ready

  const int g = blockIdx.x * 4 + w;   // 4096 groups
  const int n0 = g * 8;
  const int ebase = n0 * KNBR;
  #pragma unroll 1
  for (int mt = 0; mt < 5; ++mt) {
    const int e = mt * 16 + l15;
    const int m = knn[ebase + e];
    const int n = n0 + e / 10;
    const _Float16* Up = uu + (size_t)n * 128 + lg * 8;
    const _Float16* Vp = vv + (size_t)m * 128 + lg * 8;
    f16x8 A[4];
    #pragma unroll
    for (int ks = 0; ks < 4; ++ks) {
      f16x8 ud = *(const f16x8*)(Up + ks * 32);
      f16x8 vd = *(const f16x8*)(Vp + ks * 32);
      f16x8 df = ud - vd;                 // v_pk_sub_f16
      f16x8 t;
      #pragma unroll
      for (int j = 0; j < 8; ++j)
        t[j] = df[j] > (_Float16)0.f ? df[j] : (_Float16)0.f;  // v_pk_max_f16
      A[ks] = t;
    }
    f32x4 acc[4];
    #pragma unroll
    for (int nt = 0; nt < 4; ++nt) { float bbv = bias2[nt]; acc[nt] = (f32x4){bbv, bbv, bbv, bbv}; }
    #pragma unroll
    for (int ks = 0; ks < 4; ++ks) {
      #pragma unroll
      for (int nt = 0; nt < 4; ++nt)
        acc[nt] = __builtin_amdgcn_mfma_f32_16x16x32_f16(A[ks], w2f[ks][nt], acc[nt], 0, 0, 0);
    }
    #pragma unroll
    for (int nt = 0; nt < 4; ++nt) {
      #pragma unroll
      for (int r = 0; r < 4; ++r)
        h2w[(lg * 4 + r) * 88 + nt * 16 + l15] = (_Float16)fmaxf(acc[nt][r], 0.f);
    }
    f16x8 A3[2];
    #pragma unroll
    for (int ks2 = 0; ks2 < 2; ++ks2)
      A3[ks2] = *(const f16x8*)(h2w + l15 * 88 + ks2 * 32 + lg * 8);
    f32x4 c3[4];
    #pragma unroll
    for (int nt = 0; nt < 4; ++nt) { float bbv = bias3[nt]; c3[nt] = (f32x4){bbv, bbv, bbv, bbv}; }
    #pragma unroll
    for (int ks2 = 0; ks2 < 2; ++ks2) {
      #pragma unroll
      for (int nt = 0; nt < 4; ++nt) {
        f16x8 bf = *(const f16x8*)(W3Ts + (nt * 16 + l15) * 72 + ks2 * 32 + lg * 8);
        c3[nt] = __builtin_amdgcn_mfma_f32_16x16x32_f16(A3[ks2], bf, c3[nt], 0, 0, 0);
      }
    }
    #pragma unroll
    for (int nt = 0; nt < 4; ++nt) {
      #pragma unroll
      for (int r = 0; r < 4; ++r) {
        float val = fmaxf(c3[nt][r], 0.f);
        int e2 = mt * 16 + lg * 4 + r;
        int p = e2 / 10;
        atomicMax(&vmaxw[p * 64 + nt * 16 + l15], __float_as_int(val));
      }
    }
  }
  {
    int p2 = lane >> 3, c0 = (lane & 7) * 8;
    const int* vp = &vmaxw[p2 * 64 + c0];
    float4 r0, r1;
    r0.x = __int_as_float(vp[0]); r0.y = __int_as_float(vp[1]);
    r0.z = __int_as_float(vp[2]); r0.w = __int_as_float(vp[3]);
    r1.x = __int_as_float(vp[4]); r1.y = __int_as_float(vp[5]);
    r1.z = __int_as_float(vp[6]); r1.w = __int_as_float(vp[7]);
    *(float4*)(vert + (size_t)(n0 + p2) * 64 + c0) = r0;
    *(float4*)(vert + (size_t)(n0 + p2) * 64 + c0 + 4) = r1;
    atomicMax(&gblk[c0 + 0], __float_as_int(r0.x));
    atomicMax(&gblk[c0 + 1], __float_as_int(r0.y));
    atomicMax(&gblk[c0 + 2], __float_as_int(r0.z));
    atomicMax(&gblk[c0 + 3], __float_as_int(r0.w));
    atomicMax(&gblk[c0 + 4], __float_as_int(r1.x));
    atomicMax(&gblk[c0 + 5], __float_as_int(r1.y));
    atomicMax(&gblk[c0 + 6], __float_as_int(r1.z));
    atomicMax(&gblk[c0 + 7], __float_as_int(r1.w));
  }
  __syncthreads();
  if (tid < 64) {
    int bb2 = (blockIdx.x * 32) >> 12;   // block's batch (32 pts, single batch)
    atomicMax((int*)&gmax[bb2 * 64 + tid], gblk[tid]);
  }
}

// ---------------- K8: out = relu(vert @ Wg_top + gb[b]); gb computed in-block ----------------
__global__ void k_final(const float* __restrict__ vert, const float* __restrict__ Wg,
                        const float* __restrict__ bg, const float* __restrict__ gmax,
                        float* __restrict__ out) {
  __shared__ float Wgs[64 * 64];
  __shared__ float gbs[8 * 64];
  int tid = threadIdx.x, w = tid >> 6, lane = tid & 63;
  for (int i = tid; i < 4096; i += 256) Wgs[i] = Wg[i];  // rows 0..63
  for (int t2 = tid; t2 < 512; t2 += 256) {              // fused k_gb
    int b_ = t2 >> 6, o = t2 & 63;
    float acc = bg[o];
    #pragma unroll
    for (int i = 0; i < 64; ++i)
      acc = fmaf(gmax[b_ * 64 + i], Wg[(64 + i) * 64 + o], acc);
    gbs[t2] = acc;
  }
  __syncthreads();
  int gw = blockIdx.x * 4 + w;
  for (int j = 0; j < 4; ++j) {
    int n = gw + 8192 * j;
    int b = n >> 12;
    float vrow = vert[n * 64 + lane];
    float ac0 = gbs[b * 64 + lane], ac1 = 0.f, ac2 = 0.f, ac3 = 0.f;
    #pragma unroll
    for (int i = 0; i < 64; i += 4) {
      ac0 = fmaf(__shfl(vrow, i),     Wgs[i * 64 + lane],       ac0);
      ac1 = fmaf(__shfl(vrow, i + 1), Wgs[(i + 1) * 64 + lane], ac1);
      ac2 = fmaf(__shfl(vrow, i + 2), Wgs[(i + 2) * 64 + lane], ac2);
      ac3 = fmaf(__shfl(vrow, i + 3), Wgs[(i + 3) * 64 + lane], ac3);
    }
    out[n * 64 + lane] = fmaxf((ac0 + ac1) + (ac2 + ac3), 0.f);
  }
}

extern "C" void kernel_launch(void* const* d_in, const int* in_sizes, int n_in,
                              void* d_out, int out_size, void* d_ws, size_t ws_size,
                              hipStream_t stream) {
  const float* x     = (const float*)d_in[0];
  const float* gamma = (const float*)d_in[1];
  const float* beta  = (const float*)d_in[2];
  const float* W1    = (const float*)d_in[3];
  const float* b1    = (const float*)d_in[4];
  const float* W2    = (const float*)d_in[5];
  const float* b2    = (const float*)d_in[6];
  const float* W3    = (const float*)d_in[7];
  const float* b3    = (const float*)d_in[8];
  const float* Wg    = (const float*)d_in[9];
  const float* bg    = (const float*)d_in[10];
  float* out = (float*)d_out;

  float* ws    = (float*)d_ws;
  float* stats = ws;                    // 128
  float* ss    = ws + 128;              // 128
  float* xn    = ws + 256;              // 2097152
  float* sq    = xn + 2097152;          // 32768
  int*   knn   = (int*)(sq + 32768);    // 327680 ints
  _Float16* u  = (_Float16*)(knn + 327680);  // 4194304 halfs
  _Float16* v  = u + 4194304;                // 4194304 halfs
  float* vert  = (float*)(v + 4194304);      // 2097152
  float* g     = vert + 2097152;        // 512
  _Float16* xh = (_Float16*)(g + 512);              // 2097152 halfs
  _Float16* xl = (_Float16*)(g + 512 + 1048576);    // 2097152 halfs

  hipMemsetAsync(stats, 0, 128 * sizeof(float), stream);
  hipMemsetAsync(g, 0, 512 * sizeof(float), stream);

  k_bn_stats<<<256, 256, 0, stream>>>(x, stats);
  k_bn_finalize<<<1, 64, 0, stream>>>(stats, gamma, beta, ss);
  k_normalize<<<8192, 256, 0, stream>>>(x, ss, xn, sq, xh, xl);
  k_knn<<<512, 256, 0, stream>>>(xh, xl, sq, knn);
  k_uv<<<512, 256, 0, stream>>>(xn, W1, b1, u, v);
  k_edge<<<1024, 256, 0, stream>>>(u, v, knn, W2, b2, W3, b3, vert, g);
  k_final<<<2048, 256, 0, stream>>>(vert, Wg, bg, g, out);
}